// Round 1
// 2860.149 us; speedup vs baseline: 2.0476x; 2.0476x over previous
//
#include <hip/hip_runtime.h>
#include <cstdint>
#include <cstddef>

#define DI __device__ __forceinline__

typedef uint16_t u16;
typedef __bf16 bf16x8 __attribute__((ext_vector_type(8)));
typedef float f32x4 __attribute__((ext_vector_type(4)));

DI float b2f(u16 u) { uint32_t x = ((uint32_t)u) << 16; float f; __builtin_memcpy(&f, &x, 4); return f; }
DI u16 f2b(float f) {
    uint32_t x; __builtin_memcpy(&x, &f, 4);
    uint32_t r = (x + 0x7FFFu + ((x >> 16) & 1u)) >> 16;
    return (u16)r;
}

// Canary: fill d_out (f32) with 100+ws_MiB; final GEMM overwrites everything.
__global__ __launch_bounds__(256) void canary_kernel(float* __restrict__ out, float val) {
    size_t idx = (size_t)blockIdx.x * 256 + threadIdx.x;
    out[idx] = val;
}

// ---------------------------------------------------------------------------
// Small-weight transpose + f32->bf16 convert
// ---------------------------------------------------------------------------
__global__ __launch_bounds__(256) void transpose_weights(
    const float* __restrict__ tmw1, const float* __restrict__ tdw1,
    const float* __restrict__ tdw2, const float* __restrict__ tmw2,
    u16* __restrict__ tmw1T, u16* __restrict__ tdw1T,
    u16* __restrict__ tdw2T, u16* __restrict__ tmw2T)
{
    int idx = blockIdx.x * 256 + threadIdx.x;
    if (idx < 327680) { int r = idx / 160, c = idx % 160; tmw1T[c * 2048 + r] = f2b(tmw1[idx]); return; }
    idx -= 327680;
    if (idx < 131072) { int r = idx / 64, c = idx % 64; tdw1T[c * 2048 + r] = f2b(tdw1[idx]); return; }
    idx -= 131072;
    if (idx < 131072) { int e = idx / 2048, c = idx % 2048; tdw2T[c * 64 + e] = f2b(tdw2[idx]); return; }
    idx -= 131072;
    { int f = idx / 65536; int rem = idx % 65536; int e = rem / 2048, c = rem % 2048;
      tmw2T[f * 65536 + c * 32 + e] = f2b(tmw2[idx]); }
}

DI float block_sum(float v, float* sm) {
    #pragma unroll
    for (int off = 32; off; off >>= 1) v += __shfl_xor(v, off, 64);
    __syncthreads();
    if ((threadIdx.x & 63) == 0) sm[threadIdx.x >> 6] = v;
    __syncthreads();
    float r = sm[0] + sm[1] + sm[2] + sm[3];
    __syncthreads();
    return r;
}

// LN0 then LN1 fused: x_in(f32) -> x0b (bf16 residual), xa (bf16)
__global__ __launch_bounds__(256) void ln01_kernel(
    const float* __restrict__ xin,
    const float* __restrict__ w0, const float* __restrict__ b0,
    const float* __restrict__ w1, const float* __restrict__ b1,
    u16* __restrict__ x0b, u16* __restrict__ xa)
{
    __shared__ float sm[4];
    int row = blockIdx.x;
    int tid = threadIdx.x;
    const float* xr = xin + (size_t)row * 2048;
    float v[8];
    float s = 0.f;
    #pragma unroll
    for (int i = 0; i < 8; i++) { v[i] = xr[tid + i * 256]; s += v[i]; }
    s = block_sum(s, sm);
    float mean = s * (1.f / 2048.f);
    float q = 0.f;
    #pragma unroll
    for (int i = 0; i < 8; i++) { float d = v[i] - mean; q += d * d; }
    q = block_sum(q, sm);
    float rstd = rsqrtf(q * (1.f / 2048.f) + 1e-5f);
    float t[8];
    float s2 = 0.f;
    #pragma unroll
    for (int i = 0; i < 8; i++) {
        int c = tid + i * 256;
        t[i] = (v[i] - mean) * rstd * w0[c] + b0[c];
        x0b[(size_t)row * 2048 + c] = f2b(t[i]);
        s2 += t[i];
    }
    s2 = block_sum(s2, sm);
    float mean2 = s2 * (1.f / 2048.f);
    float q2 = 0.f;
    #pragma unroll
    for (int i = 0; i < 8; i++) { float d = t[i] - mean2; q2 += d * d; }
    q2 = block_sum(q2, sm);
    float rstd2 = rsqrtf(q2 * (1.f / 2048.f) + 1e-5f);
    #pragma unroll
    for (int i = 0; i < 8; i++) {
        int c = tid + i * 256;
        xa[(size_t)row * 2048 + c] = f2b((t[i] - mean2) * rstd2 * w1[c] + b1[c]);
    }
}

// LN over bf16 input, f32 weights -> bf16 out (LN2)
__global__ __launch_bounds__(256) void ln_bf16_kernel(
    const u16* __restrict__ xin,
    const float* __restrict__ w, const float* __restrict__ b,
    u16* __restrict__ xout)
{
    __shared__ float sm[4];
    int row = blockIdx.x;
    int tid = threadIdx.x;
    const u16* xr = xin + (size_t)row * 2048;
    float v[8];
    float s = 0.f;
    #pragma unroll
    for (int i = 0; i < 8; i++) { v[i] = b2f(xr[tid + i * 256]); s += v[i]; }
    s = block_sum(s, sm);
    float mean = s * (1.f / 2048.f);
    float q = 0.f;
    #pragma unroll
    for (int i = 0; i < 8; i++) { float d = v[i] - mean; q += d * d; }
    q = block_sum(q, sm);
    float rstd = rsqrtf(q * (1.f / 2048.f) + 1e-5f);
    #pragma unroll
    for (int i = 0; i < 8; i++) {
        int c = tid + i * 256;
        xout[(size_t)row * 2048 + c] = f2b((v[i] - mean) * rstd * w[c] + b[c]);
    }
}

// xxx = xa + (shift(xa)-xa)*maa_x
__global__ __launch_bounds__(256) void ew_xxx(
    const u16* __restrict__ xa, const float* __restrict__ maax, u16* __restrict__ xxx)
{
    size_t idx = (size_t)blockIdx.x * 256 + threadIdx.x;
    int c = (int)(idx & 2047);
    int row = (int)(idx >> 11);
    float cur = b2f(xa[idx]);
    float prev = (row & 2047) ? b2f(xa[idx - 2048]) : 0.f;
    xxx[idx] = f2b(cur + (prev - cur) * maax[c]);
}

// xk2 / xr2 for CMix
__global__ __launch_bounds__(256) void ew_shift2(
    const u16* __restrict__ xf, const float* __restrict__ cmk, const float* __restrict__ cmr,
    u16* __restrict__ xk2, u16* __restrict__ xr2)
{
    size_t idx = (size_t)blockIdx.x * 256 + threadIdx.x;
    int c = (int)(idx & 2047);
    int row = (int)(idx >> 11);
    float cur = b2f(xf[idx]);
    float prev = (row & 2047) ? b2f(xf[idx - 2048]) : 0.f;
    float xx = prev - cur;
    xk2[idx] = f2b(cur + xx * cmk[c]);
    xr2[idx] = f2b(cur + xx * cmr[c]);
}

// GroupNorm(64 per head) * lnx + bias, then * g  -> Ao (bf16)
__global__ __launch_bounds__(256) void gn_kernel(
    const float* __restrict__ y, const u16* __restrict__ g,
    const float* __restrict__ lw, const float* __restrict__ lb,
    u16* __restrict__ Ao)
{
    int grp = blockIdx.x * 4 + (threadIdx.x >> 6);
    int m = threadIdx.x & 63;
    int h = grp & 31;
    size_t idx = (size_t)grp * 64 + m;
    float v = y[idx];
    float s = v;
    #pragma unroll
    for (int off = 32; off; off >>= 1) s += __shfl_xor(s, off, 64);
    float mean = s * (1.f / 64.f);
    float d = v - mean;
    float q = d * d;
    #pragma unroll
    for (int off = 32; off; off >>= 1) q += __shfl_xor(q, off, 64);
    float rstd = rsqrtf(q * (1.f / 64.f) + 6.4e-4f);   // eps = 1e-5 * 8^2
    float yn = d * rstd * lw[h * 64 + m] + lb[h * 64 + m];
    Ao[idx] = f2b(yn * b2f(g[idx]));
}

// ---------------------------------------------------------------------------
// WKV6 chunked scan.  T=2048 split into WKV_NC chunks of WKV_L steps.
// State recurrence per (n,m): S = S*w_t[n] + k_t[n]*v_t[m]  (linear) so:
//   pass1: per-chunk, from S=0, compute M[n][m] (chunk contribution) and
//          P[n] = prod of decays.                 grid (128 bh, NC)
//   scan : S_start(c+1) = S_start(c)*P(c) + M(c); overwrite M with S_start.
//          grid (128 bh)
//   pass2: replay chunk from S_start(c), produce y.  grid (128 bh, NC)
// Scratch: Sbuf = d_out (64 MiB, dead until final GEMM), Pbuf = 1 MiB.
// ---------------------------------------------------------------------------
#define WKV_L  64
#define WKV_NC 32

__global__ __launch_bounds__(64) void wkv_pass1(
    const u16* __restrict__ kb, const u16* __restrict__ vb,
    const u16* __restrict__ wb,
    float* __restrict__ Sbuf, float* __restrict__ Pbuf)
{
    int bh = blockIdx.x;           // 0..127
    int c  = blockIdx.y;           // 0..WKV_NC-1
    int b = bh >> 5, h = bh & 31;
    int m = threadIdx.x;
    __shared__ __align__(16) float ks[64];
    __shared__ __align__(16) float ws[64];
    float S[64];
    #pragma unroll
    for (int n = 0; n < 64; n++) S[n] = 0.f;
    float P = 1.f;
    size_t base = ((size_t)b * 2048 + (size_t)(c * WKV_L)) * 2048 + (size_t)h * 64 + m;
    float kc = b2f(kb[base]), vc = b2f(vb[base]);
    float wc = __expf(-__expf(b2f(wb[base])));
    for (int t = 0; t < WKV_L; t++) {
        float kn = 0.f, vn = 0.f; u16 wn = 0;
        if (t < WKV_L - 1) {
            size_t ni = base + (size_t)(t + 1) * 2048;
            kn = b2f(kb[ni]); vn = b2f(vb[ni]); wn = wb[ni];
        }
        ks[m] = kc; ws[m] = wc;
        __syncthreads();
        #pragma unroll
        for (int g4 = 0; g4 < 16; g4++) {
            float4 k4 = *(const float4*)&ks[g4 * 4];
            float4 w4 = *(const float4*)&ws[g4 * 4];
            S[g4 * 4 + 0] = S[g4 * 4 + 0] * w4.x + k4.x * vc;
            S[g4 * 4 + 1] = S[g4 * 4 + 1] * w4.y + k4.y * vc;
            S[g4 * 4 + 2] = S[g4 * 4 + 2] * w4.z + k4.z * vc;
            S[g4 * 4 + 3] = S[g4 * 4 + 3] * w4.w + k4.w * vc;
        }
        P *= wc;
        __syncthreads();
        kc = kn; vc = vn; wc = __expf(-__expf(b2f(wn)));
    }
    size_t so = (size_t)(c * 128 + bh) * 4096 + m;
    #pragma unroll
    for (int n = 0; n < 64; n++) Sbuf[so + (size_t)n * 64] = S[n];
    Pbuf[(size_t)(c * 128 + bh) * 64 + m] = P;
}

__global__ __launch_bounds__(64) void wkv_scan(
    float* __restrict__ Sbuf, const float* __restrict__ Pbuf)
{
    int bh = blockIdx.x;
    int m = threadIdx.x;
    __shared__ float ps[64];
    float S[64];
    #pragma unroll
    for (int n = 0; n < 64; n++) S[n] = 0.f;
    for (int c = 0; c < WKV_NC; c++) {
        ps[m] = Pbuf[(size_t)(c * 128 + bh) * 64 + m];
        __syncthreads();
        size_t so = (size_t)(c * 128 + bh) * 4096 + m;
        #pragma unroll
        for (int n = 0; n < 64; n++) {
            float Mv = Sbuf[so + (size_t)n * 64];
            Sbuf[so + (size_t)n * 64] = S[n];
            S[n] = S[n] * ps[n] + Mv;
        }
        __syncthreads();
    }
}

__global__ __launch_bounds__(64) void wkv_pass2(
    const u16* __restrict__ rb, const u16* __restrict__ kb,
    const u16* __restrict__ vb, const u16* __restrict__ wb,
    const float* __restrict__ ub, const float* __restrict__ Sbuf,
    float* __restrict__ yb)
{
    int bh = blockIdx.x;
    int c  = blockIdx.y;
    int b = bh >> 5, h = bh & 31;
    int m = threadIdx.x;
    __shared__ __align__(16) float rs[64];
    __shared__ __align__(16) float ks[64];
    __shared__ __align__(16) float ws[64];
    float u_m = ub[h * 64 + m];
    float S[64];
    size_t so = (size_t)(c * 128 + bh) * 4096 + m;
    #pragma unroll
    for (int n = 0; n < 64; n++) S[n] = Sbuf[so + (size_t)n * 64];
    size_t base = ((size_t)b * 2048 + (size_t)(c * WKV_L)) * 2048 + (size_t)h * 64 + m;
    float rc = b2f(rb[base]), kc = b2f(kb[base]), vc = b2f(vb[base]);
    float wc = __expf(-__expf(b2f(wb[base])));
    for (int t = 0; t < WKV_L; t++) {
        float rn = 0.f, kn = 0.f, vn = 0.f; u16 wn = 0;
        if (t < WKV_L - 1) {
            size_t ni = base + (size_t)(t + 1) * 2048;
            rn = b2f(rb[ni]); kn = b2f(kb[ni]); vn = b2f(vb[ni]); wn = wb[ni];
        }
        rs[m] = rc; ks[m] = kc; ws[m] = wc;
        __syncthreads();
        float p = rc * u_m * kc;
        #pragma unroll
        for (int off = 32; off; off >>= 1) p += __shfl_xor(p, off, 64);
        float y = p * vc;
        #pragma unroll
        for (int g4 = 0; g4 < 16; g4++) {
            float4 r4 = *(const float4*)&rs[g4 * 4];
            float4 k4 = *(const float4*)&ks[g4 * 4];
            float4 w4 = *(const float4*)&ws[g4 * 4];
            y += r4.x * S[g4 * 4 + 0] + r4.y * S[g4 * 4 + 1]
               + r4.z * S[g4 * 4 + 2] + r4.w * S[g4 * 4 + 3];
            S[g4 * 4 + 0] = S[g4 * 4 + 0] * w4.x + k4.x * vc;
            S[g4 * 4 + 1] = S[g4 * 4 + 1] * w4.y + k4.y * vc;
            S[g4 * 4 + 2] = S[g4 * 4 + 2] * w4.z + k4.z * vc;
            S[g4 * 4 + 3] = S[g4 * 4 + 3] * w4.w + k4.w * vc;
        }
        yb[base + (size_t)t * 2048] = y;
        __syncthreads();
        rc = rn; kc = kn; vc = vn; wc = __expf(-__expf(b2f(wn)));
    }
}

// ---------------------------------------------------------------------------
// GEMM: C[M,N] = A[M,K](bf16) * W[N,K]^T.  BF32=1: W is f32, converted to
// bf16 during LDS staging. 128x128 tile, BK=32, mfma_f32_16x16x32_bf16.
// MODE: 0 plain, 1 silu, 2 relu^2, 3 sigmoid, 4 tanh,
//       5 f32bias+acc->bf16 (decay pre-act), 6 token-shift mix,
//       7 residual-add bf16, 8 final f32: x1 + s*acc
// ---------------------------------------------------------------------------
template<int MODE, int BF32>
__global__ __launch_bounds__(256)
void gemm_bt(const u16* __restrict__ A, int lda,
             const u16* __restrict__ Bh, const float* __restrict__ Bf, int ldb,
             int N, int K,
             u16* __restrict__ Cb, float* __restrict__ Cf, int ldc,
             const u16* __restrict__ auxb0,
             const u16* __restrict__ auxb1,
             const float* __restrict__ auxf0)
{
    __shared__ __align__(16) u16 At[128 * 32];
    __shared__ __align__(16) u16 Bt[128 * 32];
    const int tid = threadIdx.x;
    const int lane = tid & 63;
    const int wv = tid >> 6;
    const int wr = wv >> 1, wc = wv & 1;
    const int m0 = blockIdx.y * 128;
    const int n0 = blockIdx.x * 128;
    const int l15 = lane & 15;
    const int lq = lane >> 4;
    f32x4 acc[4][4];
    #pragma unroll
    for (int i = 0; i < 4; i++)
        #pragma unroll
        for (int j = 0; j < 4; j++) acc[i][j] = (f32x4){0.f, 0.f, 0.f, 0.f};

    for (int k0 = 0; k0 < K; k0 += 32) {
        #pragma unroll
        for (int i = 0; i < 2; i++) {
            int s = tid + i * 256;
            int row = s >> 2, kc = s & 3;
            const u16* ga = A + (size_t)(m0 + row) * lda + k0 + kc * 8;
            uint4 av = *(const uint4*)ga;
            int brow = n0 + row; brow = brow < N ? brow : N - 1;
            uint4 bv;
            if (BF32) {
                const float* gb = Bf + (size_t)brow * ldb + k0 + kc * 8;
                float4 f0 = *(const float4*)gb;
                float4 f1 = *(const float4*)(gb + 4);
                uint32_t w0 = (uint32_t)f2b(f0.x) | ((uint32_t)f2b(f0.y) << 16);
                uint32_t w1 = (uint32_t)f2b(f0.z) | ((uint32_t)f2b(f0.w) << 16);
                uint32_t w2 = (uint32_t)f2b(f1.x) | ((uint32_t)f2b(f1.y) << 16);
                uint32_t w3 = (uint32_t)f2b(f1.z) | ((uint32_t)f2b(f1.w) << 16);
                bv = make_uint4(w0, w1, w2, w3);
            } else {
                const u16* gb = Bh + (size_t)brow * ldb + k0 + kc * 8;
                bv = *(const uint4*)gb;
            }
            *(uint4*)&At[(size_t)s * 8] = av;
            *(uint4*)&Bt[(size_t)s * 8] = bv;
        }
        __syncthreads();
        bf16x8 af[4], bfr[4];
        #pragma unroll
        for (int mi = 0; mi < 4; mi++)
            af[mi] = *(const bf16x8*)(&At[(wr * 64 + mi * 16 + l15) * 32 + lq * 8]);
        #pragma unroll
        for (int ni = 0; ni < 4; ni++)
            bfr[ni] = *(const bf16x8*)(&Bt[(wc * 64 + ni * 16 + l15) * 32 + lq * 8]);
        #pragma unroll
        for (int mi = 0; mi < 4; mi++)
            #pragma unroll
            for (int ni = 0; ni < 4; ni++)
                acc[mi][ni] = __builtin_amdgcn_mfma_f32_16x16x32_bf16(af[mi], bfr[ni], acc[mi][ni], 0, 0, 0);
        __syncthreads();
    }

    #pragma unroll
    for (int ni = 0; ni < 4; ni++) {
        int col = n0 + wc * 64 + ni * 16 + l15;
        if (col >= N) continue;
        #pragma unroll
        for (int mi = 0; mi < 4; mi++) {
            int rowb = m0 + wr * 64 + mi * 16 + lq * 4;
            #pragma unroll
            for (int r = 0; r < 4; r++) {
                int row = rowb + r;
                float v = acc[mi][ni][r];
                size_t o = (size_t)row * ldc + col;
                if (MODE == 0) {
                    Cb[o] = f2b(v);
                } else if (MODE == 1) {
                    float sg = 1.f / (1.f + __expf(-v)); Cb[o] = f2b(v * sg);
                } else if (MODE == 2) {
                    float t = v > 0.f ? v : 0.f; Cb[o] = f2b(t * t);
                } else if (MODE == 3) {
                    Cb[o] = f2b(1.f / (1.f + __expf(-v)));
                } else if (MODE == 4) {
                    Cb[o] = f2b(tanhf(v));
                } else if (MODE == 5) {
                    Cb[o] = f2b(auxf0[col] + v);
                } else if (MODE == 6) {
                    float cur = b2f(auxb0[(size_t)row * 2048 + col]);
                    float prev = (row & 2047) ? b2f(auxb0[(size_t)(row - 1) * 2048 + col]) : 0.f;
                    Cb[o] = f2b(cur + (prev - cur) * (auxf0[col] + v));
                } else if (MODE == 7) {
                    Cb[o] = f2b(b2f(auxb0[o]) + v);
                } else if (MODE == 8) {
                    Cf[o] = b2f(auxb0[o]) + b2f(auxb1[o]) * v;
                }
            }
        }
    }
}

// ---------------------------------------------------------------------------
extern "C" void kernel_launch(void* const* d_in, const int* in_sizes, int n_in,
                              void* d_out, int out_size, void* d_ws, size_t ws_size,
                              hipStream_t stream)
{
    const float* x_in  = (const float*)d_in[0];
    const float* ln0w  = (const float*)d_in[1];
    const float* ln0b  = (const float*)d_in[2];
    const float* ln1w  = (const float*)d_in[3];
    const float* ln1b  = (const float*)d_in[4];
    const float* ln2w  = (const float*)d_in[5];
    const float* ln2b  = (const float*)d_in[6];
    const float* maax  = (const float*)d_in[7];
    const float* maa5  = (const float*)d_in[8];
    const float* tmw1  = (const float*)d_in[9];
    const float* tmw2  = (const float*)d_in[10];
    const float* td    = (const float*)d_in[11];
    const float* tdw1  = (const float*)d_in[12];
    const float* tdw2  = (const float*)d_in[13];
    const float* u_in  = (const float*)d_in[14];
    const float* Wr    = (const float*)d_in[15];
    const float* Wk    = (const float*)d_in[16];
    const float* Wv    = (const float*)d_in[17];
    const float* Wg    = (const float*)d_in[18];
    const float* Wo    = (const float*)d_in[19];
    const float* lnxw  = (const float*)d_in[20];
    const float* lnxb  = (const float*)d_in[21];
    const float* cmk   = (const float*)d_in[22];
    const float* cmr   = (const float*)d_in[23];
    const float* Wfk   = (const float*)d_in[24];
    const float* Wfr   = (const float*)d_in[25];
    const float* Wfv   = (const float*)d_in[26];

    const size_t MB = 1048576ULL;
    char* W = (char*)d_ws;
    u16*   xa    = (u16*)(W + 0 * MB);      // LN1 out; dead after last mix
    u16*   mslot = (u16*)(W + 32 * MB);     // xxx, then per-f mix output
    u16*   x0b   = (u16*)(W + 64 * MB);     // LN0 out (residual)
    u16*   rbuf  = (u16*)(W + 96 * MB);
    u16*   kbuf  = (u16*)(W + 128 * MB);
    u16*   vbuf  = (u16*)(W + 160 * MB);
    u16*   gbuf  = (u16*)(W + 192 * MB);
    u16*   wpre  = (u16*)(W + 224 * MB);    // bf16 pre-activation decay
    u16*   t5    = (u16*)(W + 256 * MB);    // [8192,160]
    u16*   tmw1T = (u16*)(W + 259 * MB);
    u16*   tdw1T = (u16*)(W + 260 * MB);
    u16*   tdw2T = (u16*)(W + 261 * MB);
    u16*   tmw2T = (u16*)(W + 262 * MB);
    u16*   hwb   = (u16*)(W + 263 * MB);    // [8192,64]
    // aliases (dead-range reuse):
    float* ybuf = (float*)(W + 0 * MB);     // 64MB over xa+mslot (dead post-mix)
    u16*   Ao   = rbuf;                     // post-wkv
    u16*   x1b  = kbuf;                     // post-wkv residual
    u16*   xf   = vbuf;                     // LN2 out
    u16*   xk2  = gbuf;
    u16*   xr2  = wpre;
    u16*   kf   = (u16*)(W + 0 * MB);       // [8192,7168] = 112MB over dead head
    u16*   sb   = vbuf;                     // sigmoid out (xf dead)
    // WKV chunked-scan scratch: 64MB of chunk states in d_out (dead until
    // final GEMM overwrites all of it); 1MB of decay products over dead t5.
    float* Sbuf = (float*)d_out;
    float* Pbuf = (float*)(W + 256 * MB);   // over t5 (dead after mixes)

    dim3 blk(256);
    dim3 g1(1, 64), g2(2, 64), g16(16, 64), g56(56, 64);

    float canary = 100.0f + (float)(ws_size >> 20);
    canary_kernel<<<65536, blk, 0, stream>>>((float*)d_out, canary);

    transpose_weights<<<3584, blk, 0, stream>>>(tmw1, tdw1, tdw2, tmw2, tmw1T, tdw1T, tdw2T, tmw2T);
    ln01_kernel<<<8192, blk, 0, stream>>>(x_in, ln0w, ln0b, ln1w, ln1b, x0b, xa);
    ew_xxx<<<65536, blk, 0, stream>>>(xa, maax, mslot);

    // t5 = tanh(xxx @ tm_w1)   [8192,160]
    gemm_bt<4,0><<<g2, blk, 0, stream>>>(mslot, 2048, tmw1T, nullptr, 2048, 160, 2048,
                                         t5, nullptr, 160, nullptr, nullptr, nullptr);
    // f=0 (w): mix -> mslot; hw = tanh(xw @ td_w1); wpre = td + hw @ td_w2
    gemm_bt<6,0><<<g16, blk, 0, stream>>>(t5 + 0 * 32, 160, tmw2T + 0 * 65536, nullptr, 32, 2048, 32,
                                          mslot, nullptr, 2048, xa, nullptr, maa5 + 0 * 2048);
    gemm_bt<4,0><<<g1, blk, 0, stream>>>(mslot, 2048, tdw1T, nullptr, 2048, 64, 2048,
                                         hwb, nullptr, 64, nullptr, nullptr, nullptr);
    gemm_bt<5,0><<<g16, blk, 0, stream>>>(hwb, 64, tdw2T, nullptr, 64, 2048, 64,
                                          wpre, nullptr, 2048, nullptr, nullptr, td);
    // f=1 (k)
    gemm_bt<6,0><<<g16, blk, 0, stream>>>(t5 + 1 * 32, 160, tmw2T + 1 * 65536, nullptr, 32, 2048, 32,
                                          mslot, nullptr, 2048, xa, nullptr, maa5 + 1 * 2048);
    gemm_bt<0,1><<<g16, blk, 0, stream>>>(mslot, 2048, nullptr, Wk, 2048, 2048, 2048,
                                          kbuf, nullptr, 2048, nullptr, nullptr, nullptr);
    // f=2 (v)
    gemm_bt<6,0><<<g16, blk, 0, stream>>>(t5 + 2 * 32, 160, tmw2T + 2 * 65536, nullptr, 32, 2048, 32,
                                          mslot, nullptr, 2048, xa, nullptr, maa5 + 2 * 2048);
    gemm_bt<0,1><<<g16, blk, 0, stream>>>(mslot, 2048, nullptr, Wv, 2048, 2048, 2048,
                                          vbuf, nullptr, 2048, nullptr, nullptr, nullptr);
    // f=3 (r)
    gemm_bt<6,0><<<g16, blk, 0, stream>>>(t5 + 3 * 32, 160, tmw2T + 3 * 65536, nullptr, 32, 2048, 32,
                                          mslot, nullptr, 2048, xa, nullptr, maa5 + 3 * 2048);
    gemm_bt<0,1><<<g16, blk, 0, stream>>>(mslot, 2048, nullptr, Wr, 2048, 2048, 2048,
                                          rbuf, nullptr, 2048, nullptr, nullptr, nullptr);
    // f=4 (g): silu epilogue
    gemm_bt<6,0><<<g16, blk, 0, stream>>>(t5 + 4 * 32, 160, tmw2T + 4 * 65536, nullptr, 32, 2048, 32,
                                          mslot, nullptr, 2048, xa, nullptr, maa5 + 4 * 2048);
    gemm_bt<1,1><<<g16, blk, 0, stream>>>(mslot, 2048, nullptr, Wg, 2048, 2048, 2048,
                                          gbuf, nullptr, 2048, nullptr, nullptr, nullptr);

    // WKV chunked scan -> y (fp32, overlays xa+mslot which are now dead)
    {
        dim3 gw(128, WKV_NC);
        wkv_pass1<<<gw, 64, 0, stream>>>(kbuf, vbuf, wpre, Sbuf, Pbuf);
        wkv_scan<<<128, 64, 0, stream>>>(Sbuf, Pbuf);
        wkv_pass2<<<gw, 64, 0, stream>>>(rbuf, kbuf, vbuf, wpre, u_in, Sbuf, ybuf);
    }
    // GroupNorm * g -> Ao (over rbuf)
    gn_kernel<<<65536, blk, 0, stream>>>(ybuf, gbuf, lnxw, lnxb, Ao);
    // x1 = x0 + Ao @ Wo^T  (bf16, over kbuf)
    gemm_bt<7,1><<<g16, blk, 0, stream>>>(Ao, 2048, nullptr, Wo, 2048, 2048, 2048,
                                          x1b, nullptr, 2048, x0b, nullptr, nullptr);
    // CMix
    ln_bf16_kernel<<<8192, blk, 0, stream>>>(x1b, ln2w, ln2b, xf);
    ew_shift2<<<65536, blk, 0, stream>>>(xf, cmk, cmr, xk2, xr2);
    gemm_bt<2,1><<<g56, blk, 0, stream>>>(xk2, 2048, nullptr, Wfk, 2048, 7168, 2048,
                                          kf, nullptr, 7168, nullptr, nullptr, nullptr);
    gemm_bt<3,1><<<g16, blk, 0, stream>>>(xr2, 2048, nullptr, Wfr, 2048, 2048, 2048,
                                          sb, nullptr, 2048, nullptr, nullptr, nullptr);
    gemm_bt<8,1><<<g16, blk, 0, stream>>>(kf, 7168, nullptr, Wfv, 7168, 2048, 7168,
                                          nullptr, (float*)d_out, 2048, x1b, sb, nullptr);
}

// Round 3
// 2439.663 us; speedup vs baseline: 2.4005x; 1.1724x over previous
//
#include <hip/hip_runtime.h>
#include <cstdint>
#include <cstddef>

#define DI __device__ __forceinline__

typedef uint16_t u16;
typedef __bf16 bf16x8 __attribute__((ext_vector_type(8)));
typedef float f32x4 __attribute__((ext_vector_type(4)));

DI float b2f(u16 u) { uint32_t x = ((uint32_t)u) << 16; float f; __builtin_memcpy(&f, &x, 4); return f; }
DI u16 f2b(float f) {
    uint32_t x; __builtin_memcpy(&x, &f, 4);
    uint32_t r = (x + 0x7FFFu + ((x >> 16) & 1u)) >> 16;
    return (u16)r;
}

// Async global->LDS, 16B per lane. LDS dest must be linear: uniform base + lane*16.
// Global ptr: inttoptr to AS1 (flat==global segment addresses on AMDGPU).
// LDS ptr: explicit addrspacecast from generic pointer to shared memory.
typedef const __attribute__((address_space(1))) uint32_t* gp1_t;
typedef __attribute__((address_space(3))) uint32_t* lp3_t;
DI void gld16(const void* g, void* l) {
    __builtin_amdgcn_global_load_lds((gp1_t)(uintptr_t)g, (lp3_t)l, 16, 0, 0);
}

// Canary: fill d_out (f32) with 100+ws_MiB; final GEMM overwrites everything.
__global__ __launch_bounds__(256) void canary_kernel(float* __restrict__ out, float val) {
    size_t idx = (size_t)blockIdx.x * 256 + threadIdx.x;
    out[idx] = val;
}

// ---------------------------------------------------------------------------
// Weight convert f32 -> bf16 (elementwise, vectorized 8/thread, grid-stride)
// ---------------------------------------------------------------------------
__global__ __launch_bounds__(256) void conv_w(
    const float* __restrict__ in, u16* __restrict__ out, int n8)
{
    int idx = blockIdx.x * 256 + threadIdx.x;
    int stride = gridDim.x * 256;
    for (int i = idx; i < n8; i += stride) {
        const float4* p = (const float4*)(in + (size_t)i * 8);
        float4 a = p[0], b = p[1];
        uint32_t w0 = (uint32_t)f2b(a.x) | ((uint32_t)f2b(a.y) << 16);
        uint32_t w1 = (uint32_t)f2b(a.z) | ((uint32_t)f2b(a.w) << 16);
        uint32_t w2 = (uint32_t)f2b(b.x) | ((uint32_t)f2b(b.y) << 16);
        uint32_t w3 = (uint32_t)f2b(b.z) | ((uint32_t)f2b(b.w) << 16);
        *(uint4*)(out + (size_t)i * 8) = make_uint4(w0, w1, w2, w3);
    }
}

// ---------------------------------------------------------------------------
// Small-weight transpose + f32->bf16 convert
// ---------------------------------------------------------------------------
__global__ __launch_bounds__(256) void transpose_weights(
    const float* __restrict__ tmw1, const float* __restrict__ tdw1,
    const float* __restrict__ tdw2, const float* __restrict__ tmw2,
    u16* __restrict__ tmw1T, u16* __restrict__ tdw1T,
    u16* __restrict__ tdw2T, u16* __restrict__ tmw2T)
{
    int idx = blockIdx.x * 256 + threadIdx.x;
    if (idx < 327680) { int r = idx / 160, c = idx % 160; tmw1T[c * 2048 + r] = f2b(tmw1[idx]); return; }
    idx -= 327680;
    if (idx < 131072) { int r = idx / 64, c = idx % 64; tdw1T[c * 2048 + r] = f2b(tdw1[idx]); return; }
    idx -= 131072;
    if (idx < 131072) { int e = idx / 2048, c = idx % 2048; tdw2T[c * 64 + e] = f2b(tdw2[idx]); return; }
    idx -= 131072;
    { int f = idx / 65536; int rem = idx % 65536; int e = rem / 2048, c = rem % 2048;
      tmw2T[f * 65536 + c * 32 + e] = f2b(tmw2[idx]); }
}

DI float block_sum(float v, float* sm) {
    #pragma unroll
    for (int off = 32; off; off >>= 1) v += __shfl_xor(v, off, 64);
    __syncthreads();
    if ((threadIdx.x & 63) == 0) sm[threadIdx.x >> 6] = v;
    __syncthreads();
    float r = sm[0] + sm[1] + sm[2] + sm[3];
    __syncthreads();
    return r;
}

// LN0 then LN1 fused: x_in(f32) -> x0b (bf16 residual), xa (bf16)
__global__ __launch_bounds__(256) void ln01_kernel(
    const float* __restrict__ xin,
    const float* __restrict__ w0, const float* __restrict__ b0,
    const float* __restrict__ w1, const float* __restrict__ b1,
    u16* __restrict__ x0b, u16* __restrict__ xa)
{
    __shared__ float sm[4];
    int row = blockIdx.x;
    int tid = threadIdx.x;
    const float* xr = xin + (size_t)row * 2048;
    float v[8];
    float s = 0.f;
    #pragma unroll
    for (int i = 0; i < 8; i++) { v[i] = xr[tid + i * 256]; s += v[i]; }
    s = block_sum(s, sm);
    float mean = s * (1.f / 2048.f);
    float q = 0.f;
    #pragma unroll
    for (int i = 0; i < 8; i++) { float d = v[i] - mean; q += d * d; }
    q = block_sum(q, sm);
    float rstd = rsqrtf(q * (1.f / 2048.f) + 1e-5f);
    float t[8];
    float s2 = 0.f;
    #pragma unroll
    for (int i = 0; i < 8; i++) {
        int c = tid + i * 256;
        t[i] = (v[i] - mean) * rstd * w0[c] + b0[c];
        x0b[(size_t)row * 2048 + c] = f2b(t[i]);
        s2 += t[i];
    }
    s2 = block_sum(s2, sm);
    float mean2 = s2 * (1.f / 2048.f);
    float q2 = 0.f;
    #pragma unroll
    for (int i = 0; i < 8; i++) { float d = t[i] - mean2; q2 += d * d; }
    q2 = block_sum(q2, sm);
    float rstd2 = rsqrtf(q2 * (1.f / 2048.f) + 1e-5f);
    #pragma unroll
    for (int i = 0; i < 8; i++) {
        int c = tid + i * 256;
        xa[(size_t)row * 2048 + c] = f2b((t[i] - mean2) * rstd2 * w1[c] + b1[c]);
    }
}

// LN over bf16 input, f32 weights -> bf16 out (LN2)
__global__ __launch_bounds__(256) void ln_bf16_kernel(
    const u16* __restrict__ xin,
    const float* __restrict__ w, const float* __restrict__ b,
    u16* __restrict__ xout)
{
    __shared__ float sm[4];
    int row = blockIdx.x;
    int tid = threadIdx.x;
    const u16* xr = xin + (size_t)row * 2048;
    float v[8];
    float s = 0.f;
    #pragma unroll
    for (int i = 0; i < 8; i++) { v[i] = b2f(xr[tid + i * 256]); s += v[i]; }
    s = block_sum(s, sm);
    float mean = s * (1.f / 2048.f);
    float q = 0.f;
    #pragma unroll
    for (int i = 0; i < 8; i++) { float d = v[i] - mean; q += d * d; }
    q = block_sum(q, sm);
    float rstd = rsqrtf(q * (1.f / 2048.f) + 1e-5f);
    #pragma unroll
    for (int i = 0; i < 8; i++) {
        int c = tid + i * 256;
        xout[(size_t)row * 2048 + c] = f2b((v[i] - mean) * rstd * w[c] + b[c]);
    }
}

// xxx = xa + (shift(xa)-xa)*maa_x
__global__ __launch_bounds__(256) void ew_xxx(
    const u16* __restrict__ xa, const float* __restrict__ maax, u16* __restrict__ xxx)
{
    size_t idx = (size_t)blockIdx.x * 256 + threadIdx.x;
    int c = (int)(idx & 2047);
    int row = (int)(idx >> 11);
    float cur = b2f(xa[idx]);
    float prev = (row & 2047) ? b2f(xa[idx - 2048]) : 0.f;
    xxx[idx] = f2b(cur + (prev - cur) * maax[c]);
}

// single-output token-shift mix (CMix): out = xf + (shift(xf)-xf)*coef
__global__ __launch_bounds__(256) void ew_shift_one(
    const u16* __restrict__ xf, const float* __restrict__ coef, u16* __restrict__ out)
{
    size_t idx = (size_t)blockIdx.x * 256 + threadIdx.x;
    int c = (int)(idx & 2047);
    int row = (int)(idx >> 11);
    float cur = b2f(xf[idx]);
    float prev = (row & 2047) ? b2f(xf[idx - 2048]) : 0.f;
    out[idx] = f2b(cur + (prev - cur) * coef[c]);
}

// GroupNorm(64 per head) * lnx + bias, then * g  -> Ao (bf16)
__global__ __launch_bounds__(256) void gn_kernel(
    const float* __restrict__ y, const u16* __restrict__ g,
    const float* __restrict__ lw, const float* __restrict__ lb,
    u16* __restrict__ Ao)
{
    int grp = blockIdx.x * 4 + (threadIdx.x >> 6);
    int m = threadIdx.x & 63;
    int h = grp & 31;
    size_t idx = (size_t)grp * 64 + m;
    float v = y[idx];
    float s = v;
    #pragma unroll
    for (int off = 32; off; off >>= 1) s += __shfl_xor(s, off, 64);
    float mean = s * (1.f / 64.f);
    float d = v - mean;
    float q = d * d;
    #pragma unroll
    for (int off = 32; off; off >>= 1) q += __shfl_xor(q, off, 64);
    float rstd = rsqrtf(q * (1.f / 64.f) + 6.4e-4f);   // eps = 1e-5 * 8^2
    float yn = d * rstd * lw[h * 64 + m] + lb[h * 64 + m];
    Ao[idx] = f2b(yn * b2f(g[idx]));
}

// ---------------------------------------------------------------------------
// WKV6 chunked scan (pass1 / scan / pass2). Sbuf = d_out, Pbuf over dead t5.
// ---------------------------------------------------------------------------
#define WKV_L  64
#define WKV_NC 32

__global__ __launch_bounds__(64) void wkv_pass1(
    const u16* __restrict__ kb, const u16* __restrict__ vb,
    const u16* __restrict__ wb,
    float* __restrict__ Sbuf, float* __restrict__ Pbuf)
{
    int bh = blockIdx.x;           // 0..127
    int c  = blockIdx.y;           // 0..WKV_NC-1
    int b = bh >> 5, h = bh & 31;
    int m = threadIdx.x;
    __shared__ __align__(16) float ks[64];
    __shared__ __align__(16) float ws[64];
    float S[64];
    #pragma unroll
    for (int n = 0; n < 64; n++) S[n] = 0.f;
    float P = 1.f;
    size_t base = ((size_t)b * 2048 + (size_t)(c * WKV_L)) * 2048 + (size_t)h * 64 + m;
    float kc = b2f(kb[base]), vc = b2f(vb[base]);
    float wc = __expf(-__expf(b2f(wb[base])));
    for (int t = 0; t < WKV_L; t++) {
        float kn = 0.f, vn = 0.f; u16 wn = 0;
        if (t < WKV_L - 1) {
            size_t ni = base + (size_t)(t + 1) * 2048;
            kn = b2f(kb[ni]); vn = b2f(vb[ni]); wn = wb[ni];
        }
        ks[m] = kc; ws[m] = wc;
        __syncthreads();
        #pragma unroll
        for (int g4 = 0; g4 < 16; g4++) {
            float4 k4 = *(const float4*)&ks[g4 * 4];
            float4 w4 = *(const float4*)&ws[g4 * 4];
            S[g4 * 4 + 0] = S[g4 * 4 + 0] * w4.x + k4.x * vc;
            S[g4 * 4 + 1] = S[g4 * 4 + 1] * w4.y + k4.y * vc;
            S[g4 * 4 + 2] = S[g4 * 4 + 2] * w4.z + k4.z * vc;
            S[g4 * 4 + 3] = S[g4 * 4 + 3] * w4.w + k4.w * vc;
        }
        P *= wc;
        __syncthreads();
        kc = kn; vc = vn; wc = __expf(-__expf(b2f(wn)));
    }
    size_t so = (size_t)(c * 128 + bh) * 4096 + m;
    #pragma unroll
    for (int n = 0; n < 64; n++) Sbuf[so + (size_t)n * 64] = S[n];
    Pbuf[(size_t)(c * 128 + bh) * 64 + m] = P;
}

__global__ __launch_bounds__(64) void wkv_scan(
    float* __restrict__ Sbuf, const float* __restrict__ Pbuf)
{
    int bh = blockIdx.x;
    int m = threadIdx.x;
    __shared__ float ps[64];
    float S[64];
    #pragma unroll
    for (int n = 0; n < 64; n++) S[n] = 0.f;
    for (int c = 0; c < WKV_NC; c++) {
        ps[m] = Pbuf[(size_t)(c * 128 + bh) * 64 + m];
        __syncthreads();
        size_t so = (size_t)(c * 128 + bh) * 4096 + m;
        #pragma unroll
        for (int n = 0; n < 64; n++) {
            float Mv = Sbuf[so + (size_t)n * 64];
            Sbuf[so + (size_t)n * 64] = S[n];
            S[n] = S[n] * ps[n] + Mv;
        }
        __syncthreads();
    }
}

__global__ __launch_bounds__(64) void wkv_pass2(
    const u16* __restrict__ rb, const u16* __restrict__ kb,
    const u16* __restrict__ vb, const u16* __restrict__ wb,
    const float* __restrict__ ub, const float* __restrict__ Sbuf,
    float* __restrict__ yb)
{
    int bh = blockIdx.x;
    int c  = blockIdx.y;
    int b = bh >> 5, h = bh & 31;
    int m = threadIdx.x;
    __shared__ __align__(16) float rs[64];
    __shared__ __align__(16) float ks[64];
    __shared__ __align__(16) float ws[64];
    float u_m = ub[h * 64 + m];
    float S[64];
    size_t so = (size_t)(c * 128 + bh) * 4096 + m;
    #pragma unroll
    for (int n = 0; n < 64; n++) S[n] = Sbuf[so + (size_t)n * 64];
    size_t base = ((size_t)b * 2048 + (size_t)(c * WKV_L)) * 2048 + (size_t)h * 64 + m;
    float rc = b2f(rb[base]), kc = b2f(kb[base]), vc = b2f(vb[base]);
    float wc = __expf(-__expf(b2f(wb[base])));
    for (int t = 0; t < WKV_L; t++) {
        float rn = 0.f, kn = 0.f, vn = 0.f; u16 wn = 0;
        if (t < WKV_L - 1) {
            size_t ni = base + (size_t)(t + 1) * 2048;
            rn = b2f(rb[ni]); kn = b2f(kb[ni]); vn = b2f(vb[ni]); wn = wb[ni];
        }
        rs[m] = rc; ks[m] = kc; ws[m] = wc;
        __syncthreads();
        float p = rc * u_m * kc;
        #pragma unroll
        for (int off = 32; off; off >>= 1) p += __shfl_xor(p, off, 64);
        float y = p * vc;
        #pragma unroll
        for (int g4 = 0; g4 < 16; g4++) {
            float4 r4 = *(const float4*)&rs[g4 * 4];
            float4 k4 = *(const float4*)&ks[g4 * 4];
            float4 w4 = *(const float4*)&ws[g4 * 4];
            y += r4.x * S[g4 * 4 + 0] + r4.y * S[g4 * 4 + 1]
               + r4.z * S[g4 * 4 + 2] + r4.w * S[g4 * 4 + 3];
            S[g4 * 4 + 0] = S[g4 * 4 + 0] * w4.x + k4.x * vc;
            S[g4 * 4 + 1] = S[g4 * 4 + 1] * w4.y + k4.y * vc;
            S[g4 * 4 + 2] = S[g4 * 4 + 2] * w4.z + k4.z * vc;
            S[g4 * 4 + 3] = S[g4 * 4 + 3] * w4.w + k4.w * vc;
        }
        yb[base + (size_t)t * 2048] = y;
        __syncthreads();
        rc = rn; kc = kn; vc = vn; wc = __expf(-__expf(b2f(wn)));
    }
}

// ---------------------------------------------------------------------------
// GEMM: C[M,N] = A[M,K](bf16) * W[N,K]^T (bf16). 128x128 tile, BK=32,
// mfma_f32_16x16x32_bf16, global_load_lds(16B) staging for A and B.
// MODE: 0 plain, 1 silu, 2 relu^2, 3 sigmoid, 4 tanh,
//       5 f32bias+acc->bf16 (decay pre-act), 6 token-shift mix,
//       7 residual-add bf16, 8 final f32: x1 + s*acc
// ---------------------------------------------------------------------------
template<int MODE>
__global__ __launch_bounds__(256)
void gemm_bt(const u16* __restrict__ A, int lda,
             const u16* __restrict__ B, int ldb,
             int N, int K,
             u16* __restrict__ Cb, float* __restrict__ Cf, int ldc,
             const u16* __restrict__ auxb0,
             const u16* __restrict__ auxb1,
             const float* __restrict__ auxf0)
{
    __shared__ __align__(16) u16 At[128 * 32];
    __shared__ __align__(16) u16 Bt[128 * 32];
    const int tid = threadIdx.x;
    const int lane = tid & 63;
    const int wv = tid >> 6;
    const int wr = wv >> 1, wc = wv & 1;
    const int m0 = blockIdx.y * 128;
    const int n0 = blockIdx.x * 128;
    const int l15 = lane & 15;
    const int lq = lane >> 4;
    f32x4 acc[4][4];
    #pragma unroll
    for (int i = 0; i < 4; i++)
        #pragma unroll
        for (int j = 0; j < 4; j++) acc[i][j] = (f32x4){0.f, 0.f, 0.f, 0.f};

    // staging geometry: thread s in [0,512) covers 8 u16 at linear LDS offset
    // s*16B; row = s>>2, k-chunk = (s&3)*8.  LDS dest = uniform base + lane*16.
    const int s0 = tid, s1 = tid + 256;
    const int rA0 = s0 >> 2, kc0 = (s0 & 3) * 8;
    const int rA1 = s1 >> 2, kc1 = (s1 & 3) * 8;
    const u16* ga0 = A + (size_t)(m0 + rA0) * lda + kc0;
    const u16* ga1 = A + (size_t)(m0 + rA1) * lda + kc1;
    int br0 = n0 + rA0; br0 = br0 < N ? br0 : N - 1;
    int br1 = n0 + rA1; br1 = br1 < N ? br1 : N - 1;
    const u16* gb0 = B + (size_t)br0 * ldb + kc0;
    const u16* gb1 = B + (size_t)br1 * ldb + kc1;
    u16* la0 = &At[(size_t)s0 * 8];
    u16* la1 = &At[(size_t)s1 * 8];
    u16* lb0 = &Bt[(size_t)s0 * 8];
    u16* lb1 = &Bt[(size_t)s1 * 8];

    for (int k0 = 0; k0 < K; k0 += 32) {
        gld16(ga0 + k0, la0);
        gld16(ga1 + k0, la1);
        gld16(gb0 + k0, lb0);
        gld16(gb1 + k0, lb1);
        __syncthreads();
        bf16x8 af[4], bfr[4];
        #pragma unroll
        for (int mi = 0; mi < 4; mi++)
            af[mi] = *(const bf16x8*)(&At[(wr * 64 + mi * 16 + l15) * 32 + lq * 8]);
        #pragma unroll
        for (int ni = 0; ni < 4; ni++)
            bfr[ni] = *(const bf16x8*)(&Bt[(wc * 64 + ni * 16 + l15) * 32 + lq * 8]);
        #pragma unroll
        for (int mi = 0; mi < 4; mi++)
            #pragma unroll
            for (int ni = 0; ni < 4; ni++)
                acc[mi][ni] = __builtin_amdgcn_mfma_f32_16x16x32_bf16(af[mi], bfr[ni], acc[mi][ni], 0, 0, 0);
        __syncthreads();
    }

    #pragma unroll
    for (int ni = 0; ni < 4; ni++) {
        int col = n0 + wc * 64 + ni * 16 + l15;
        if (col >= N) continue;
        #pragma unroll
        for (int mi = 0; mi < 4; mi++) {
            int rowb = m0 + wr * 64 + mi * 16 + lq * 4;
            #pragma unroll
            for (int r = 0; r < 4; r++) {
                int row = rowb + r;
                float v = acc[mi][ni][r];
                size_t o = (size_t)row * ldc + col;
                if (MODE == 0) {
                    Cb[o] = f2b(v);
                } else if (MODE == 1) {
                    float sg = 1.f / (1.f + __expf(-v)); Cb[o] = f2b(v * sg);
                } else if (MODE == 2) {
                    float t = v > 0.f ? v : 0.f; Cb[o] = f2b(t * t);
                } else if (MODE == 3) {
                    Cb[o] = f2b(1.f / (1.f + __expf(-v)));
                } else if (MODE == 4) {
                    Cb[o] = f2b(tanhf(v));
                } else if (MODE == 5) {
                    Cb[o] = f2b(auxf0[col] + v);
                } else if (MODE == 6) {
                    float cur = b2f(auxb0[(size_t)row * 2048 + col]);
                    float prev = (row & 2047) ? b2f(auxb0[(size_t)(row - 1) * 2048 + col]) : 0.f;
                    Cb[o] = f2b(cur + (prev - cur) * (auxf0[col] + v));
                } else if (MODE == 7) {
                    Cb[o] = f2b(b2f(auxb0[o]) + v);
                } else if (MODE == 8) {
                    Cf[o] = b2f(auxb0[o]) + b2f(auxb1[o]) * v;
                }
            }
        }
    }
}

// ---------------------------------------------------------------------------
extern "C" void kernel_launch(void* const* d_in, const int* in_sizes, int n_in,
                              void* d_out, int out_size, void* d_ws, size_t ws_size,
                              hipStream_t stream)
{
    const float* x_in  = (const float*)d_in[0];
    const float* ln0w  = (const float*)d_in[1];
    const float* ln0b  = (const float*)d_in[2];
    const float* ln1w  = (const float*)d_in[3];
    const float* ln1b  = (const float*)d_in[4];
    const float* ln2w  = (const float*)d_in[5];
    const float* ln2b  = (const float*)d_in[6];
    const float* maax  = (const float*)d_in[7];
    const float* maa5  = (const float*)d_in[8];
    const float* tmw1  = (const float*)d_in[9];
    const float* tmw2  = (const float*)d_in[10];
    const float* td    = (const float*)d_in[11];
    const float* tdw1  = (const float*)d_in[12];
    const float* tdw2  = (const float*)d_in[13];
    const float* u_in  = (const float*)d_in[14];
    const float* Wr    = (const float*)d_in[15];
    const float* Wk    = (const float*)d_in[16];
    const float* Wv    = (const float*)d_in[17];
    const float* Wg    = (const float*)d_in[18];
    const float* Wo    = (const float*)d_in[19];
    const float* lnxw  = (const float*)d_in[20];
    const float* lnxb  = (const float*)d_in[21];
    const float* cmk   = (const float*)d_in[22];
    const float* cmr   = (const float*)d_in[23];
    const float* Wfk   = (const float*)d_in[24];
    const float* Wfr   = (const float*)d_in[25];
    const float* Wfv   = (const float*)d_in[26];

    const size_t MB = 1048576ULL;
    char* W = (char*)d_ws;
    u16*   xa    = (u16*)(W + 0 * MB);      // LN1 out; dead after last mix
    u16*   mslot = (u16*)(W + 32 * MB);     // xxx, then per-f mix output
    u16*   x0b   = (u16*)(W + 64 * MB);     // LN0 out (residual)
    u16*   rbuf  = (u16*)(W + 96 * MB);
    u16*   kbuf  = (u16*)(W + 128 * MB);
    u16*   vbuf  = (u16*)(W + 160 * MB);
    u16*   gbuf  = (u16*)(W + 192 * MB);
    u16*   wpre  = (u16*)(W + 224 * MB);    // bf16 pre-activation decay
    u16*   t5    = (u16*)(W + 256 * MB);    // [8192,160]
    u16*   tmw1T = (u16*)(W + 259 * MB);
    u16*   tdw1T = (u16*)(W + 260 * MB);
    u16*   tdw2T = (u16*)(W + 261 * MB);
    u16*   tmw2T = (u16*)(W + 262 * MB);
    u16*   hwb   = (u16*)(W + 263 * MB);    // [8192,64]
    // aliases (dead-range reuse):
    float* ybuf = (float*)(W + 0 * MB);     // 64MB over xa+mslot (dead post-mix)
    u16*   Ao   = rbuf;                     // post-wkv
    u16*   x1b  = kbuf;                     // post-wkv residual
    u16*   xf   = vbuf;                     // LN2 out
    u16*   xk2  = gbuf;
    u16*   xr2  = wpre;                     // written AFTER Wfk gemm (scratch dies)
    u16*   kf   = (u16*)(W + 0 * MB);       // [8192,7168] = 112MB over dead head
    u16*   sb   = vbuf;                     // sigmoid out (xf dead)
    // WKV chunked-scan scratch: 64MB in d_out (dead until final GEMM); 1MB Pbuf.
    float* Sbuf = (float*)d_out;
    float* Pbuf = (float*)(W + 256 * MB);   // over t5 (dead after mixes)
    // JIT bf16 weight scratch (lifetime-audited dead ranges):
    u16* wsKV = rbuf;                       // Wk, then Wv (rbuf free until f=3)
    u16* wsR  = gbuf;                       // Wr (gbuf free until f=4)
    u16* wsG  = xa;                         // Wg (xa dead after last mix)
    u16* wsO  = (u16*)(W + 0 * MB);         // Wo (ybuf dead after gn)
    u16* wsFK = wpre;                       // Wfk (wpre dead after wkv; 28MB<32MB)
    u16* wsFR = (u16*)(W + 112 * MB);       // Wfr (Ao tail dead; 8MB<16MB)
    u16* wsFV = gbuf;                       // Wfv (xk2 dead after Wfk gemm; 28MB)

    dim3 blk(256);
    dim3 g1(1, 64), g2(2, 64), g16(16, 64), g56(56, 64);
    const int N8sq = 2048 * 2048 / 8;       // 2048^2 weights / 8
    const int N8ff = 7168 * 2048 / 8;       // FFN weights / 8

    float canary = 100.0f + (float)(ws_size >> 20);
    canary_kernel<<<65536, blk, 0, stream>>>((float*)d_out, canary);

    transpose_weights<<<3584, blk, 0, stream>>>(tmw1, tdw1, tdw2, tmw2, tmw1T, tdw1T, tdw2T, tmw2T);
    ln01_kernel<<<8192, blk, 0, stream>>>(x_in, ln0w, ln0b, ln1w, ln1b, x0b, xa);
    ew_xxx<<<65536, blk, 0, stream>>>(xa, maax, mslot);

    // t5 = tanh(xxx @ tm_w1)   [8192,160]
    gemm_bt<4><<<g2, blk, 0, stream>>>(mslot, 2048, tmw1T, 2048, 160, 2048,
                                       t5, nullptr, 160, nullptr, nullptr, nullptr);
    // f=0 (w): mix -> mslot; hw = tanh(xw @ td_w1); wpre = td + hw @ td_w2
    gemm_bt<6><<<g16, blk, 0, stream>>>(t5 + 0 * 32, 160, tmw2T + 0 * 65536, 32, 2048, 32,
                                        mslot, nullptr, 2048, xa, nullptr, maa5 + 0 * 2048);
    gemm_bt<4><<<g1, blk, 0, stream>>>(mslot, 2048, tdw1T, 2048, 64, 2048,
                                       hwb, nullptr, 64, nullptr, nullptr, nullptr);
    gemm_bt<5><<<g16, blk, 0, stream>>>(hwb, 64, tdw2T, 64, 2048, 64,
                                        wpre, nullptr, 2048, nullptr, nullptr, td);
    // f=1 (k)
    gemm_bt<6><<<g16, blk, 0, stream>>>(t5 + 1 * 32, 160, tmw2T + 1 * 65536, 32, 2048, 32,
                                        mslot, nullptr, 2048, xa, nullptr, maa5 + 1 * 2048);
    conv_w<<<2048, blk, 0, stream>>>(Wk, wsKV, N8sq);
    gemm_bt<0><<<g16, blk, 0, stream>>>(mslot, 2048, wsKV, 2048, 2048, 2048,
                                        kbuf, nullptr, 2048, nullptr, nullptr, nullptr);
    // f=2 (v)
    gemm_bt<6><<<g16, blk, 0, stream>>>(t5 + 2 * 32, 160, tmw2T + 2 * 65536, 32, 2048, 32,
                                        mslot, nullptr, 2048, xa, nullptr, maa5 + 2 * 2048);
    conv_w<<<2048, blk, 0, stream>>>(Wv, wsKV, N8sq);
    gemm_bt<0><<<g16, blk, 0, stream>>>(mslot, 2048, wsKV, 2048, 2048, 2048,
                                        vbuf, nullptr, 2048, nullptr, nullptr, nullptr);
    // f=3 (r)
    gemm_bt<6><<<g16, blk, 0, stream>>>(t5 + 3 * 32, 160, tmw2T + 3 * 65536, 32, 2048, 32,
                                        mslot, nullptr, 2048, xa, nullptr, maa5 + 3 * 2048);
    conv_w<<<2048, blk, 0, stream>>>(Wr, wsR, N8sq);
    gemm_bt<0><<<g16, blk, 0, stream>>>(mslot, 2048, wsR, 2048, 2048, 2048,
                                        rbuf, nullptr, 2048, nullptr, nullptr, nullptr);
    // f=4 (g): mix is the LAST read of xa; then Wg scratch overlays xa.
    gemm_bt<6><<<g16, blk, 0, stream>>>(t5 + 4 * 32, 160, tmw2T + 4 * 65536, 32, 2048, 32,
                                        mslot, nullptr, 2048, xa, nullptr, maa5 + 4 * 2048);
    conv_w<<<2048, blk, 0, stream>>>(Wg, wsG, N8sq);
    gemm_bt<1><<<g16, blk, 0, stream>>>(mslot, 2048, wsG, 2048, 2048, 2048,
                                        gbuf, nullptr, 2048, nullptr, nullptr, nullptr);

    // WKV chunked scan -> y (fp32, overlays xa+mslot which are now dead)
    {
        dim3 gw(128, WKV_NC);
        wkv_pass1<<<gw, 64, 0, stream>>>(kbuf, vbuf, wpre, Sbuf, Pbuf);
        wkv_scan<<<128, 64, 0, stream>>>(Sbuf, Pbuf);
        wkv_pass2<<<gw, 64, 0, stream>>>(rbuf, kbuf, vbuf, wpre, u_in, Sbuf, ybuf);
    }
    // GroupNorm * g -> Ao (over rbuf)
    gn_kernel<<<65536, blk, 0, stream>>>(ybuf, gbuf, lnxw, lnxb, Ao);
    // x1 = x0 + Ao @ Wo^T  (bf16, over kbuf); Wo scratch over dead ybuf
    conv_w<<<2048, blk, 0, stream>>>(Wo, wsO, N8sq);
    gemm_bt<7><<<g16, blk, 0, stream>>>(Ao, 2048, wsO, 2048, 2048, 2048,
                                        x1b, nullptr, 2048, x0b, nullptr, nullptr);
    // CMix
    ln_bf16_kernel<<<8192, blk, 0, stream>>>(x1b, ln2w, ln2b, xf);
    ew_shift_one<<<65536, blk, 0, stream>>>(xf, cmk, xk2);
    conv_w<<<2048, blk, 0, stream>>>(Wfk, wsFK, N8ff);
    gemm_bt<2><<<g56, blk, 0, stream>>>(xk2, 2048, wsFK, 2048, 7168, 2048,
                                        kf, nullptr, 7168, nullptr, nullptr, nullptr);
    // xr2 written over dead Wfk scratch; xf still live until here
    ew_shift_one<<<65536, blk, 0, stream>>>(xf, cmr, xr2);
    conv_w<<<2048, blk, 0, stream>>>(Wfr, wsFR, N8sq);
    gemm_bt<3><<<g16, blk, 0, stream>>>(xr2, 2048, wsFR, 2048, 2048, 2048,
                                        sb, nullptr, 2048, nullptr, nullptr, nullptr);
    conv_w<<<2048, blk, 0, stream>>>(Wfv, wsFV, N8ff);
    gemm_bt<8><<<g16, blk, 0, stream>>>(kf, 7168, wsFV, 7168, 2048, 7168,
                                        nullptr, (float*)d_out, 2048, x1b, sb, nullptr);
}

// Round 5
// 1987.813 us; speedup vs baseline: 2.9461x; 1.2273x over previous
//
#include <hip/hip_runtime.h>
#include <cstdint>
#include <cstddef>

#define DI __device__ __forceinline__

typedef uint16_t u16;
typedef __bf16 bf16x8 __attribute__((ext_vector_type(8)));
typedef float f32x4 __attribute__((ext_vector_type(4)));

DI float b2f(u16 u) { uint32_t x = ((uint32_t)u) << 16; float f; __builtin_memcpy(&f, &x, 4); return f; }
DI u16 f2b(float f) {
    uint32_t x; __builtin_memcpy(&x, &f, 4);
    uint32_t r = (x + 0x7FFFu + ((x >> 16) & 1u)) >> 16;
    return (u16)r;
}

// Async global->LDS, 16B per lane. LDS dest must be linear: uniform base + lane*16.
typedef const __attribute__((address_space(1))) uint32_t* gp1_t;
typedef __attribute__((address_space(3))) uint32_t* lp3_t;
DI void gld16(const void* g, void* l) {
    __builtin_amdgcn_global_load_lds((gp1_t)(uintptr_t)g, (lp3_t)l, 16, 0, 0);
}

#define BARRIER()  asm volatile("s_barrier" ::: "memory")
#define VMCNT4()   asm volatile("s_waitcnt vmcnt(4)" ::: "memory")
#define VMCNT2()   asm volatile("s_waitcnt vmcnt(2)" ::: "memory")
#define VMCNT0()   asm volatile("s_waitcnt vmcnt(0)" ::: "memory")

// Canary: fill d_out (f32) with 100+ws_MiB; final GEMM overwrites everything.
__global__ __launch_bounds__(256) void canary_kernel(float* __restrict__ out, float val) {
    size_t idx = (size_t)blockIdx.x * 256 + threadIdx.x;
    out[idx] = val;
}

// ---------------------------------------------------------------------------
// Weight convert f32 -> bf16 (elementwise, vectorized 8/thread, grid-stride)
// ---------------------------------------------------------------------------
__global__ __launch_bounds__(256) void conv_w(
    const float* __restrict__ in, u16* __restrict__ out, int n8)
{
    int idx = blockIdx.x * 256 + threadIdx.x;
    int stride = gridDim.x * 256;
    for (int i = idx; i < n8; i += stride) {
        const float4* p = (const float4*)(in + (size_t)i * 8);
        float4 a = p[0], b = p[1];
        uint32_t w0 = (uint32_t)f2b(a.x) | ((uint32_t)f2b(a.y) << 16);
        uint32_t w1 = (uint32_t)f2b(a.z) | ((uint32_t)f2b(a.w) << 16);
        uint32_t w2 = (uint32_t)f2b(b.x) | ((uint32_t)f2b(b.y) << 16);
        uint32_t w3 = (uint32_t)f2b(b.z) | ((uint32_t)f2b(b.w) << 16);
        *(uint4*)(out + (size_t)i * 8) = make_uint4(w0, w1, w2, w3);
    }
}

// ---------------------------------------------------------------------------
// Small-weight transpose + f32->bf16 convert
// ---------------------------------------------------------------------------
__global__ __launch_bounds__(256) void transpose_weights(
    const float* __restrict__ tmw1, const float* __restrict__ tdw1,
    const float* __restrict__ tdw2, const float* __restrict__ tmw2,
    u16* __restrict__ tmw1T, u16* __restrict__ tdw1T,
    u16* __restrict__ tdw2T, u16* __restrict__ tmw2T)
{
    int idx = blockIdx.x * 256 + threadIdx.x;
    if (idx < 327680) { int r = idx / 160, c = idx % 160; tmw1T[c * 2048 + r] = f2b(tmw1[idx]); return; }
    idx -= 327680;
    if (idx < 131072) { int r = idx / 64, c = idx % 64; tdw1T[c * 2048 + r] = f2b(tdw1[idx]); return; }
    idx -= 131072;
    if (idx < 131072) { int e = idx / 2048, c = idx % 2048; tdw2T[c * 64 + e] = f2b(tdw2[idx]); return; }
    idx -= 131072;
    { int f = idx / 65536; int rem = idx % 65536; int e = rem / 2048, c = rem % 2048;
      tmw2T[f * 65536 + c * 32 + e] = f2b(tmw2[idx]); }
}

DI float block_sum(float v, float* sm) {
    #pragma unroll
    for (int off = 32; off; off >>= 1) v += __shfl_xor(v, off, 64);
    __syncthreads();
    if ((threadIdx.x & 63) == 0) sm[threadIdx.x >> 6] = v;
    __syncthreads();
    float r = sm[0] + sm[1] + sm[2] + sm[3];
    __syncthreads();
    return r;
}

// LN0 then LN1 fused: x_in(f32) -> x0b (bf16 residual), xa (bf16)
__global__ __launch_bounds__(256) void ln01_kernel(
    const float* __restrict__ xin,
    const float* __restrict__ w0, const float* __restrict__ b0,
    const float* __restrict__ w1, const float* __restrict__ b1,
    u16* __restrict__ x0b, u16* __restrict__ xa)
{
    __shared__ float sm[4];
    int row = blockIdx.x;
    int tid = threadIdx.x;
    const float* xr = xin + (size_t)row * 2048;
    float v[8];
    float s = 0.f;
    #pragma unroll
    for (int i = 0; i < 8; i++) { v[i] = xr[tid + i * 256]; s += v[i]; }
    s = block_sum(s, sm);
    float mean = s * (1.f / 2048.f);
    float q = 0.f;
    #pragma unroll
    for (int i = 0; i < 8; i++) { float d = v[i] - mean; q += d * d; }
    q = block_sum(q, sm);
    float rstd = rsqrtf(q * (1.f / 2048.f) + 1e-5f);
    float t[8];
    float s2 = 0.f;
    #pragma unroll
    for (int i = 0; i < 8; i++) {
        int c = tid + i * 256;
        t[i] = (v[i] - mean) * rstd * w0[c] + b0[c];
        x0b[(size_t)row * 2048 + c] = f2b(t[i]);
        s2 += t[i];
    }
    s2 = block_sum(s2, sm);
    float mean2 = s2 * (1.f / 2048.f);
    float q2 = 0.f;
    #pragma unroll
    for (int i = 0; i < 8; i++) { float d = t[i] - mean2; q2 += d * d; }
    q2 = block_sum(q2, sm);
    float rstd2 = rsqrtf(q2 * (1.f / 2048.f) + 1e-5f);
    #pragma unroll
    for (int i = 0; i < 8; i++) {
        int c = tid + i * 256;
        xa[(size_t)row * 2048 + c] = f2b((t[i] - mean2) * rstd2 * w1[c] + b1[c]);
    }
}

// LN over bf16 input, f32 weights -> bf16 out (LN2)
__global__ __launch_bounds__(256) void ln_bf16_kernel(
    const u16* __restrict__ xin,
    const float* __restrict__ w, const float* __restrict__ b,
    u16* __restrict__ xout)
{
    __shared__ float sm[4];
    int row = blockIdx.x;
    int tid = threadIdx.x;
    const u16* xr = xin + (size_t)row * 2048;
    float v[8];
    float s = 0.f;
    #pragma unroll
    for (int i = 0; i < 8; i++) { v[i] = b2f(xr[tid + i * 256]); s += v[i]; }
    s = block_sum(s, sm);
    float mean = s * (1.f / 2048.f);
    float q = 0.f;
    #pragma unroll
    for (int i = 0; i < 8; i++) { float d = v[i] - mean; q += d * d; }
    q = block_sum(q, sm);
    float rstd = rsqrtf(q * (1.f / 2048.f) + 1e-5f);
    #pragma unroll
    for (int i = 0; i < 8; i++) {
        int c = tid + i * 256;
        xout[(size_t)row * 2048 + c] = f2b((v[i] - mean) * rstd * w[c] + b[c]);
    }
}

// xxx = xa + (shift(xa)-xa)*maa_x
__global__ __launch_bounds__(256) void ew_xxx(
    const u16* __restrict__ xa, const float* __restrict__ maax, u16* __restrict__ xxx)
{
    size_t idx = (size_t)blockIdx.x * 256 + threadIdx.x;
    int c = (int)(idx & 2047);
    int row = (int)(idx >> 11);
    float cur = b2f(xa[idx]);
    float prev = (row & 2047) ? b2f(xa[idx - 2048]) : 0.f;
    xxx[idx] = f2b(cur + (prev - cur) * maax[c]);
}

// single-output token-shift mix (CMix): out = xf + (shift(xf)-xf)*coef
__global__ __launch_bounds__(256) void ew_shift_one(
    const u16* __restrict__ xf, const float* __restrict__ coef, u16* __restrict__ out)
{
    size_t idx = (size_t)blockIdx.x * 256 + threadIdx.x;
    int c = (int)(idx & 2047);
    int row = (int)(idx >> 11);
    float cur = b2f(xf[idx]);
    float prev = (row & 2047) ? b2f(xf[idx - 2048]) : 0.f;
    out[idx] = f2b(cur + (prev - cur) * coef[c]);
}

// GroupNorm(64 per head) * lnx + bias, then * g  -> Ao (bf16)
__global__ __launch_bounds__(256) void gn_kernel(
    const float* __restrict__ y, const u16* __restrict__ g,
    const float* __restrict__ lw, const float* __restrict__ lb,
    u16* __restrict__ Ao)
{
    int grp = blockIdx.x * 4 + (threadIdx.x >> 6);
    int m = threadIdx.x & 63;
    int h = grp & 31;
    size_t idx = (size_t)grp * 64 + m;
    float v = y[idx];
    float s = v;
    #pragma unroll
    for (int off = 32; off; off >>= 1) s += __shfl_xor(s, off, 64);
    float mean = s * (1.f / 64.f);
    float d = v - mean;
    float q = d * d;
    #pragma unroll
    for (int off = 32; off; off >>= 1) q += __shfl_xor(q, off, 64);
    float rstd = rsqrtf(q * (1.f / 64.f) + 6.4e-4f);   // eps = 1e-5 * 8^2
    float yn = d * rstd * lw[h * 64 + m] + lb[h * 64 + m];
    Ao[idx] = f2b(yn * b2f(g[idx]));
}

// ---------------------------------------------------------------------------
// WKV6 chunked scan (pass1 / scan / pass2). Sbuf = d_out, Pbuf over dead t5.
// ---------------------------------------------------------------------------
#define WKV_L  64
#define WKV_NC 32

__global__ __launch_bounds__(64) void wkv_pass1(
    const u16* __restrict__ kb, const u16* __restrict__ vb,
    const u16* __restrict__ wb,
    float* __restrict__ Sbuf, float* __restrict__ Pbuf)
{
    int bh = blockIdx.x;           // 0..127
    int c  = blockIdx.y;           // 0..WKV_NC-1
    int b = bh >> 5, h = bh & 31;
    int m = threadIdx.x;
    __shared__ __align__(16) float ks[64];
    __shared__ __align__(16) float ws[64];
    float S[64];
    #pragma unroll
    for (int n = 0; n < 64; n++) S[n] = 0.f;
    float P = 1.f;
    size_t base = ((size_t)b * 2048 + (size_t)(c * WKV_L)) * 2048 + (size_t)h * 64 + m;
    float kc = b2f(kb[base]), vc = b2f(vb[base]);
    float wc = __expf(-__expf(b2f(wb[base])));
    for (int t = 0; t < WKV_L; t++) {
        float kn = 0.f, vn = 0.f; u16 wn = 0;
        if (t < WKV_L - 1) {
            size_t ni = base + (size_t)(t + 1) * 2048;
            kn = b2f(kb[ni]); vn = b2f(vb[ni]); wn = wb[ni];
        }
        ks[m] = kc; ws[m] = wc;
        __syncthreads();
        #pragma unroll
        for (int g4 = 0; g4 < 16; g4++) {
            float4 k4 = *(const float4*)&ks[g4 * 4];
            float4 w4 = *(const float4*)&ws[g4 * 4];
            S[g4 * 4 + 0] = S[g4 * 4 + 0] * w4.x + k4.x * vc;
            S[g4 * 4 + 1] = S[g4 * 4 + 1] * w4.y + k4.y * vc;
            S[g4 * 4 + 2] = S[g4 * 4 + 2] * w4.z + k4.z * vc;
            S[g4 * 4 + 3] = S[g4 * 4 + 3] * w4.w + k4.w * vc;
        }
        P *= wc;
        __syncthreads();
        kc = kn; vc = vn; wc = __expf(-__expf(b2f(wn)));
    }
    size_t so = (size_t)(c * 128 + bh) * 4096 + m;
    #pragma unroll
    for (int n = 0; n < 64; n++) Sbuf[so + (size_t)n * 64] = S[n];
    Pbuf[(size_t)(c * 128 + bh) * 64 + m] = P;
}

__global__ __launch_bounds__(64) void wkv_scan(
    float* __restrict__ Sbuf, const float* __restrict__ Pbuf)
{
    int bh = blockIdx.x;
    int m = threadIdx.x;
    __shared__ float ps[64];
    float S[64];
    #pragma unroll
    for (int n = 0; n < 64; n++) S[n] = 0.f;
    for (int c = 0; c < WKV_NC; c++) {
        ps[m] = Pbuf[(size_t)(c * 128 + bh) * 64 + m];
        __syncthreads();
        size_t so = (size_t)(c * 128 + bh) * 4096 + m;
        #pragma unroll
        for (int n = 0; n < 64; n++) {
            float Mv = Sbuf[so + (size_t)n * 64];
            Sbuf[so + (size_t)n * 64] = S[n];
            S[n] = S[n] * ps[n] + Mv;
        }
        __syncthreads();
    }
}

__global__ __launch_bounds__(64) void wkv_pass2(
    const u16* __restrict__ rb, const u16* __restrict__ kb,
    const u16* __restrict__ vb, const u16* __restrict__ wb,
    const float* __restrict__ ub, const float* __restrict__ Sbuf,
    float* __restrict__ yb)
{
    int bh = blockIdx.x;
    int c  = blockIdx.y;
    int b = bh >> 5, h = bh & 31;
    int m = threadIdx.x;
    __shared__ __align__(16) float rs[64];
    __shared__ __align__(16) float ks[64];
    __shared__ __align__(16) float ws[64];
    float u_m = ub[h * 64 + m];
    float S[64];
    size_t so = (size_t)(c * 128 + bh) * 4096 + m;
    #pragma unroll
    for (int n = 0; n < 64; n++) S[n] = Sbuf[so + (size_t)n * 64];
    size_t base = ((size_t)b * 2048 + (size_t)(c * WKV_L)) * 2048 + (size_t)h * 64 + m;
    float rc = b2f(rb[base]), kc = b2f(kb[base]), vc = b2f(vb[base]);
    float wc = __expf(-__expf(b2f(wb[base])));
    for (int t = 0; t < WKV_L; t++) {
        float rn = 0.f, kn = 0.f, vn = 0.f; u16 wn = 0;
        if (t < WKV_L - 1) {
            size_t ni = base + (size_t)(t + 1) * 2048;
            rn = b2f(rb[ni]); kn = b2f(kb[ni]); vn = b2f(vb[ni]); wn = wb[ni];
        }
        rs[m] = rc; ks[m] = kc; ws[m] = wc;
        __syncthreads();
        float p = rc * u_m * kc;
        #pragma unroll
        for (int off = 32; off; off >>= 1) p += __shfl_xor(p, off, 64);
        float y = p * vc;
        #pragma unroll
        for (int g4 = 0; g4 < 16; g4++) {
            float4 r4 = *(const float4*)&rs[g4 * 4];
            float4 k4 = *(const float4*)&ks[g4 * 4];
            float4 w4 = *(const float4*)&ws[g4 * 4];
            y += r4.x * S[g4 * 4 + 0] + r4.y * S[g4 * 4 + 1]
               + r4.z * S[g4 * 4 + 2] + r4.w * S[g4 * 4 + 3];
            S[g4 * 4 + 0] = S[g4 * 4 + 0] * w4.x + k4.x * vc;
            S[g4 * 4 + 1] = S[g4 * 4 + 1] * w4.y + k4.y * vc;
            S[g4 * 4 + 2] = S[g4 * 4 + 2] * w4.z + k4.z * vc;
            S[g4 * 4 + 3] = S[g4 * 4 + 3] * w4.w + k4.w * vc;
        }
        yb[base + (size_t)t * 2048] = y;
        __syncthreads();
        rc = rn; kc = kn; vc = vn; wc = __expf(-__expf(b2f(wn)));
    }
}

// ---------------------------------------------------------------------------
// 256x256 4-phase-per-tile GEMM: C[M,N] = A[M,K] * W[N,K]^T, all bf16.
// BK=64, 8 waves. Phase P=(QM,QN) computes C-quadrant [QM*128,+128)x[QN*128,+128);
// within it the 8 waves tile 2Mx4N (64x32 each). Phase P reads ONLY A-half QM
// and B-half QN -> halves may land progressively (counted vmcnt, no drain).
// Stage order for tile t+1: A0@ph0, B0@ph1, B1@ph2, A1@ph3.
// vmcnt(4) at ph0/ph1/ph3 ends (last tile: vmcnt(2)/vmcnt(0)/-).
// XOR-swizzled LDS (slot ^= row&7) via pre-swizzled global source (rule 21).
// Requires M%256==0, N%256==0, K%64==0 (>=128), grid%8==0 (T1 swizzle).
// ---------------------------------------------------------------------------
template<int P>
DI void loadq(bf16x8 (&a_)[4][2], bf16x8 (&b_)[2][2],
              const u16* Ab, const u16* Bb, int abase, int bbase) {
    constexpr int QM = P >> 1, QN = P & 1;
    #pragma unroll
    for (int i = 0; i < 4; ++i) {
        int o = abase + QM * 16384 + i * 2048;
        a_[i][0] = *(const bf16x8*)((const char*)Ab + o);
        a_[i][1] = *(const bf16x8*)((const char*)Ab + (o ^ 64));
    }
    #pragma unroll
    for (int j = 0; j < 2; ++j) {
        int o = bbase + QN * 16384 + j * 2048;
        b_[j][0] = *(const bf16x8*)((const char*)Bb + o);
        b_[j][1] = *(const bf16x8*)((const char*)Bb + (o ^ 64));
    }
}
template<int P>
DI void mfq(f32x4 (&acc)[4][4][2], const bf16x8 (&a_)[4][2], const bf16x8 (&b_)[2][2]) {
    #pragma unroll
    for (int i = 0; i < 4; ++i)
        #pragma unroll
        for (int j = 0; j < 2; ++j) {
            acc[P][i][j] = __builtin_amdgcn_mfma_f32_16x16x32_bf16(
                a_[i][0], b_[j][0], acc[P][i][j], 0, 0, 0);
            acc[P][i][j] = __builtin_amdgcn_mfma_f32_16x16x32_bf16(
                a_[i][1], b_[j][1], acc[P][i][j], 0, 0, 0);
        }
}

// MODE: 0 plain, 1 silu, 2 relu^2, 3 sigmoid, 7 residual-add bf16,
//       8 final f32: aux0 + aux1*acc
template<int MODE>
__global__ __launch_bounds__(512, 2)
void gemm256(const u16* __restrict__ A, int lda,
             const u16* __restrict__ B, int ldb,
             int K, int nxb,
             u16* __restrict__ Cb, float* __restrict__ Cf, int ldc,
             const u16* __restrict__ auxb0, const u16* __restrict__ auxb1)
{
    __shared__ __align__(16) u16 Al[2][16384];
    __shared__ __align__(16) u16 Bl[2][16384];

    // T1: bijective XCD swizzle (gridDim.x % 8 == 0 at all call sites)
    int nwg = gridDim.x;
    int cpx = nwg >> 3;
    int sw = (blockIdx.x & 7) * cpx + (blockIdx.x >> 3);
    int mb = sw / nxb, nb = sw - mb * nxb;
    int m0 = mb * 256, n0 = nb * 256;

    int tid = threadIdx.x;
    int lane = tid & 63;
    int wid = tid >> 6;
    int vm = wid >> 2, vn = wid & 3;
    int l15 = lane & 15, q = lane >> 4;

    // staging: slot s covers 16B; row = s>>3, global k-chunk pre-swizzled
    int s0 = tid, s1 = tid + 512;
    int r0 = s0 >> 3, r1 = s1 >> 3;
    int k0e = (((s0 & 7) ^ (r0 & 7)) << 3);
    int k1e = (((s1 & 7) ^ (r1 & 7)) << 3);
    const u16* gA00 = A + (size_t)(m0 +       r0) * lda + k0e;
    const u16* gA01 = A + (size_t)(m0 +       r1) * lda + k1e;
    const u16* gA10 = A + (size_t)(m0 + 128 + r0) * lda + k0e;
    const u16* gA11 = A + (size_t)(m0 + 128 + r1) * lda + k1e;
    const u16* gB00 = B + (size_t)(n0 +       r0) * ldb + k0e;
    const u16* gB01 = B + (size_t)(n0 +       r1) * ldb + k1e;
    const u16* gB10 = B + (size_t)(n0 + 128 + r0) * ldb + k0e;
    const u16* gB11 = B + (size_t)(n0 + 128 + r1) * ldb + k1e;
    int d00 = s0 * 8, d01 = s1 * 8;           // u16 index, half0 (rows 0-127)
    int d10 = 8192 + s0 * 8, d11 = 8192 + s1 * 8;   // half1 (rows 128-255)

    // ds_read byte offsets (swizzled): row stride 128B, slot = chunk ^ (row&7)
    int swz0 = q ^ (l15 & 7);
    int abase = (vm * 64 + l15) * 128 + swz0 * 16;
    int bbase = (vn * 32 + l15) * 128 + swz0 * 16;

    f32x4 acc[4][4][2];
    #pragma unroll
    for (int p = 0; p < 4; ++p)
        #pragma unroll
        for (int i = 0; i < 4; ++i)
            #pragma unroll
            for (int j = 0; j < 2; ++j) acc[p][i][j] = (f32x4){0.f, 0.f, 0.f, 0.f};

    int nt = K >> 6;

    // prologue: stage tile 0 in order A0, B0, B1, A1
    gld16(gA00, &Al[0][d00]); gld16(gA01, &Al[0][d01]);
    gld16(gB00, &Bl[0][d00]); gld16(gB01, &Bl[0][d01]);
    gld16(gB10, &Bl[0][d10]); gld16(gB11, &Bl[0][d11]);
    gld16(gA10, &Al[0][d10]); gld16(gA11, &Al[0][d11]);
    VMCNT4();      // A0,B0 landed
    BARRIER();

    for (int t = 0; t < nt; ++t) {
        const u16* Ab = &Al[t & 1][0];
        const u16* Bb = &Bl[t & 1][0];
        int stb = (t & 1) ^ 1;
        bool st = (t + 1 < nt);
        size_t ko = (size_t)(t + 1) * 64;
        bf16x8 a_[4][2], b_[2][2];

        // ph0: quadrant (0,0) [reads A0,B0]; stage A0(t+1)
        loadq<0>(a_, b_, Ab, Bb, abase, bbase);
        if (st) { gld16(gA00 + ko, &Al[stb][d00]); gld16(gA01 + ko, &Al[stb][d01]); VMCNT4(); }
        else    { VMCNT2(); }
        BARRIER();                      // B1(t) now visible to all
        __builtin_amdgcn_s_setprio(1);
        mfq<0>(acc, a_, b_);
        __builtin_amdgcn_s_setprio(0);

        // ph1: quadrant (0,1) [reads A0,B1]; stage B0(t+1)
        loadq<1>(a_, b_, Ab, Bb, abase, bbase);
        if (st) { gld16(gB00 + ko, &Bl[stb][d00]); gld16(gB01 + ko, &Bl[stb][d01]); VMCNT4(); }
        else    { VMCNT0(); }
        BARRIER();                      // A1(t) now visible
        __builtin_amdgcn_s_setprio(1);
        mfq<1>(acc, a_, b_);
        __builtin_amdgcn_s_setprio(0);

        // ph2: quadrant (1,0) [reads A1,B0]; stage B1(t+1)
        loadq<2>(a_, b_, Ab, Bb, abase, bbase);
        if (st) { gld16(gB10 + ko, &Bl[stb][d10]); gld16(gB11 + ko, &Bl[stb][d11]); }
        BARRIER();
        __builtin_amdgcn_s_setprio(1);
        mfq<2>(acc, a_, b_);
        __builtin_amdgcn_s_setprio(0);

        // ph3: quadrant (1,1) [reads A1,B1]; stage A1(t+1)
        loadq<3>(a_, b_, Ab, Bb, abase, bbase);
        if (st) { gld16(gA10 + ko, &Al[stb][d10]); gld16(gA11 + ko, &Al[stb][d11]); VMCNT4(); }
        BARRIER();                      // A0,B0(t+1) now visible
        __builtin_amdgcn_s_setprio(1);
        mfq<3>(acc, a_, b_);
        __builtin_amdgcn_s_setprio(0);
    }

    // epilogue: phase P=(QM,QN): rows m0+QM*128+vm*64+[0,64), cols n0+QN*128+vn*32+[0,32)
    #pragma unroll
    for (int p = 0; p < 4; ++p) {
        int qm = p >> 1, qn = p & 1;
        #pragma unroll
        for (int mi = 0; mi < 4; ++mi) {
            #pragma unroll
            for (int nj = 0; nj < 2; ++nj) {
                int col = n0 + qn * 128 + vn * 32 + nj * 16 + l15;
                int rowb = m0 + qm * 128 + vm * 64 + mi * 16 + q * 4;
                #pragma unroll
                for (int r = 0; r < 4; ++r) {
                    int row = rowb + r;
                    float v = acc[p][mi][nj][r];
                    size_t o = (size_t)row * ldc + col;
                    if (MODE == 0) {
                        Cb[o] = f2b(v);
                    } else if (MODE == 1) {
                        float sg = 1.f / (1.f + __expf(-v)); Cb[o] = f2b(v * sg);
                    } else if (MODE == 2) {
                        float tq = v > 0.f ? v : 0.f; Cb[o] = f2b(tq * tq);
                    } else if (MODE == 3) {
                        Cb[o] = f2b(1.f / (1.f + __expf(-v)));
                    } else if (MODE == 7) {
                        Cb[o] = f2b(b2f(auxb0[o]) + v);
                    } else if (MODE == 8) {
                        Cf[o] = b2f(auxb0[o]) + b2f(auxb1[o]) * v;
                    }
                }
            }
        }
    }
}

// ---------------------------------------------------------------------------
// Legacy 128x128 GEMM for small/odd shapes (N=160/64, K=32/64, token-shift mix)
// MODE: 4 tanh, 5 f32bias+acc->bf16, 6 token-shift mix
// ---------------------------------------------------------------------------
template<int MODE>
__global__ __launch_bounds__(256)
void gemm_bt(const u16* __restrict__ A, int lda,
             const u16* __restrict__ B, int ldb,
             int N, int K,
             u16* __restrict__ Cb, float* __restrict__ Cf, int ldc,
             const u16* __restrict__ auxb0,
             const u16* __restrict__ auxb1,
             const float* __restrict__ auxf0)
{
    __shared__ __align__(16) u16 At[128 * 32];
    __shared__ __align__(16) u16 Bt[128 * 32];
    const int tid = threadIdx.x;
    const int lane = tid & 63;
    const int wv = tid >> 6;
    const int wr = wv >> 1, wc = wv & 1;
    const int m0 = blockIdx.y * 128;
    const int n0 = blockIdx.x * 128;
    const int l15 = lane & 15;
    const int lq = lane >> 4;
    f32x4 acc[4][4];
    #pragma unroll
    for (int i = 0; i < 4; i++)
        #pragma unroll
        for (int j = 0; j < 4; j++) acc[i][j] = (f32x4){0.f, 0.f, 0.f, 0.f};

    const int s0 = tid, s1 = tid + 256;
    const int rA0 = s0 >> 2, kc0 = (s0 & 3) * 8;
    const int rA1 = s1 >> 2, kc1 = (s1 & 3) * 8;
    const u16* ga0 = A + (size_t)(m0 + rA0) * lda + kc0;
    const u16* ga1 = A + (size_t)(m0 + rA1) * lda + kc1;
    int br0 = n0 + rA0; br0 = br0 < N ? br0 : N - 1;
    int br1 = n0 + rA1; br1 = br1 < N ? br1 : N - 1;
    const u16* gb0 = B + (size_t)br0 * ldb + kc0;
    const u16* gb1 = B + (size_t)br1 * ldb + kc1;
    u16* la0 = &At[(size_t)s0 * 8];
    u16* la1 = &At[(size_t)s1 * 8];
    u16* lb0 = &Bt[(size_t)s0 * 8];
    u16* lb1 = &Bt[(size_t)s1 * 8];

    for (int k0 = 0; k0 < K; k0 += 32) {
        gld16(ga0 + k0, la0);
        gld16(ga1 + k0, la1);
        gld16(gb0 + k0, lb0);
        gld16(gb1 + k0, lb1);
        __syncthreads();
        bf16x8 af[4], bfr[4];
        #pragma unroll
        for (int mi = 0; mi < 4; mi++)
            af[mi] = *(const bf16x8*)(&At[(wr * 64 + mi * 16 + l15) * 32 + lq * 8]);
        #pragma unroll
        for (int ni = 0; ni < 4; ni++)
            bfr[ni] = *(const bf16x8*)(&Bt[(wc * 64 + ni * 16 + l15) * 32 + lq * 8]);
        #pragma unroll
        for (int mi = 0; mi < 4; mi++)
            #pragma unroll
            for (int ni = 0; ni < 4; ni++)
                acc[mi][ni] = __builtin_amdgcn_mfma_f32_16x16x32_bf16(af[mi], bfr[ni], acc[mi][ni], 0, 0, 0);
        __syncthreads();
    }

    #pragma unroll
    for (int ni = 0; ni < 4; ni++) {
        int col = n0 + wc * 64 + ni * 16 + l15;
        if (col >= N) continue;
        #pragma unroll
        for (int mi = 0; mi < 4; mi++) {
            int rowb = m0 + wr * 64 + mi * 16 + lq * 4;
            #pragma unroll
            for (int r = 0; r < 4; r++) {
                int row = rowb + r;
                float v = acc[mi][ni][r];
                size_t o = (size_t)row * ldc + col;
                if (MODE == 0) {
                    Cb[o] = f2b(v);
                } else if (MODE == 4) {
                    Cb[o] = f2b(tanhf(v));
                } else if (MODE == 5) {
                    Cb[o] = f2b(auxf0[col] + v);
                } else if (MODE == 6) {
                    float cur = b2f(auxb0[(size_t)row * 2048 + col]);
                    float prev = (row & 2047) ? b2f(auxb0[(size_t)(row - 1) * 2048 + col]) : 0.f;
                    Cb[o] = f2b(cur + (prev - cur) * (auxf0[col] + v));
                }
            }
        }
    }
}

// ---------------------------------------------------------------------------
extern "C" void kernel_launch(void* const* d_in, const int* in_sizes, int n_in,
                              void* d_out, int out_size, void* d_ws, size_t ws_size,
                              hipStream_t stream)
{
    const float* x_in  = (const float*)d_in[0];
    const float* ln0w  = (const float*)d_in[1];
    const float* ln0b  = (const float*)d_in[2];
    const float* ln1w  = (const float*)d_in[3];
    const float* ln1b  = (const float*)d_in[4];
    const float* ln2w  = (const float*)d_in[5];
    const float* ln2b  = (const float*)d_in[6];
    const float* maax  = (const float*)d_in[7];
    const float* maa5  = (const float*)d_in[8];
    const float* tmw1  = (const float*)d_in[9];
    const float* tmw2  = (const float*)d_in[10];
    const float* td    = (const float*)d_in[11];
    const float* tdw1  = (const float*)d_in[12];
    const float* tdw2  = (const float*)d_in[13];
    const float* u_in  = (const float*)d_in[14];
    const float* Wr    = (const float*)d_in[15];
    const float* Wk    = (const float*)d_in[16];
    const float* Wv    = (const float*)d_in[17];
    const float* Wg    = (const float*)d_in[18];
    const float* Wo    = (const float*)d_in[19];
    const float* lnxw  = (const float*)d_in[20];
    const float* lnxb  = (const float*)d_in[21];
    const float* cmk   = (const float*)d_in[22];
    const float* cmr   = (const float*)d_in[23];
    const float* Wfk   = (const float*)d_in[24];
    const float* Wfr   = (const float*)d_in[25];
    const float* Wfv   = (const float*)d_in[26];

    const size_t MB = 1048576ULL;
    char* W = (char*)d_ws;
    u16*   xa    = (u16*)(W + 0 * MB);      // LN1 out; dead after last mix
    u16*   mslot = (u16*)(W + 32 * MB);     // xxx, then per-f mix output
    u16*   x0b   = (u16*)(W + 64 * MB);     // LN0 out (residual)
    u16*   rbuf  = (u16*)(W + 96 * MB);
    u16*   kbuf  = (u16*)(W + 128 * MB);
    u16*   vbuf  = (u16*)(W + 160 * MB);
    u16*   gbuf  = (u16*)(W + 192 * MB);
    u16*   wpre  = (u16*)(W + 224 * MB);    // bf16 pre-activation decay
    u16*   t5    = (u16*)(W + 256 * MB);    // [8192,160]
    u16*   tmw1T = (u16*)(W + 259 * MB);
    u16*   tdw1T = (u16*)(W + 260 * MB);
    u16*   tdw2T = (u16*)(W + 261 * MB);
    u16*   tmw2T = (u16*)(W + 262 * MB);
    u16*   hwb   = (u16*)(W + 263 * MB);    // [8192,64]
    // aliases (dead-range reuse):
    float* ybuf = (float*)(W + 0 * MB);     // 64MB over xa+mslot (dead post-mix)
    u16*   Ao   = rbuf;                     // post-wkv
    u16*   x1b  = kbuf;                     // post-wkv residual
    u16*   xf   = vbuf;                     // LN2 out
    u16*   xk2  = gbuf;
    u16*   xr2  = wpre;                     // written AFTER Wfk gemm (scratch dies)
    u16*   kf   = (u16*)(W + 0 * MB);       // [8192,7168] = 112MB over dead head
    u16*   sgb  = vbuf;                     // sigmoid out (xf dead)
    // WKV chunked-scan scratch: 64MB in d_out (dead until final GEMM); 1MB Pbuf.
    float* Sbuf = (float*)d_out;
    float* Pbuf = (float*)(W + 256 * MB);   // over t5 (dead after mixes)
    // JIT bf16 weight scratch (lifetime-audited dead ranges):
    u16* wsKV = rbuf;                       // Wk, then Wv (rbuf free until f=3)
    u16* wsR  = gbuf;                       // Wr (gbuf free until f=4)
    u16* wsG  = xa;                         // Wg (xa dead after last mix)
    u16* wsO  = (u16*)(W + 0 * MB);         // Wo (ybuf dead after gn)
    u16* wsFK = wpre;                       // Wfk (wpre dead after wkv; 28MB<32MB)
    u16* wsFR = (u16*)(W + 112 * MB);       // Wfr (Ao tail dead; 8MB<16MB)
    u16* wsFV = gbuf;                       // Wfv (xk2 dead after Wfk gemm; 28MB)

    dim3 blk(256);
    dim3 g1(1, 64), g2(2, 64), g16(16, 64);
    const int N8sq = 2048 * 2048 / 8;
    const int N8ff = 7168 * 2048 / 8;
    // 256-tile grid sizes: (M/256)*(N/256); nxb = N/256
    const int GB_SQ = 32 * 8;    // 256 blocks, nxb=8
    const int GB_FK = 32 * 28;   // 896 blocks, nxb=28

    float canary = 100.0f + (float)(ws_size >> 20);
    canary_kernel<<<65536, blk, 0, stream>>>((float*)d_out, canary);

    transpose_weights<<<3584, blk, 0, stream>>>(tmw1, tdw1, tdw2, tmw2, tmw1T, tdw1T, tdw2T, tmw2T);
    ln01_kernel<<<8192, blk, 0, stream>>>(x_in, ln0w, ln0b, ln1w, ln1b, x0b, xa);
    ew_xxx<<<65536, blk, 0, stream>>>(xa, maax, mslot);

    // t5 = tanh(xxx @ tm_w1)   [8192,160]
    gemm_bt<4><<<g2, blk, 0, stream>>>(mslot, 2048, tmw1T, 2048, 160, 2048,
                                       t5, nullptr, 160, nullptr, nullptr, nullptr);
    // f=0 (w): mix -> mslot; hw = tanh(xw @ td_w1); wpre = td + hw @ td_w2
    gemm_bt<6><<<g16, blk, 0, stream>>>(t5 + 0 * 32, 160, tmw2T + 0 * 65536, 32, 2048, 32,
                                        mslot, nullptr, 2048, xa, nullptr, maa5 + 0 * 2048);
    gemm_bt<4><<<g1, blk, 0, stream>>>(mslot, 2048, tdw1T, 2048, 64, 2048,
                                       hwb, nullptr, 64, nullptr, nullptr, nullptr);
    gemm_bt<5><<<g16, blk, 0, stream>>>(hwb, 64, tdw2T, 64, 2048, 64,
                                        wpre, nullptr, 2048, nullptr, nullptr, td);
    // f=1 (k)
    gemm_bt<6><<<g16, blk, 0, stream>>>(t5 + 1 * 32, 160, tmw2T + 1 * 65536, 32, 2048, 32,
                                        mslot, nullptr, 2048, xa, nullptr, maa5 + 1 * 2048);
    conv_w<<<2048, blk, 0, stream>>>(Wk, wsKV, N8sq);
    gemm256<0><<<GB_SQ, 512, 0, stream>>>(mslot, 2048, wsKV, 2048, 2048, 8,
                                          kbuf, nullptr, 2048, nullptr, nullptr);
    // f=2 (v)
    gemm_bt<6><<<g16, blk, 0, stream>>>(t5 + 2 * 32, 160, tmw2T + 2 * 65536, 32, 2048, 32,
                                        mslot, nullptr, 2048, xa, nullptr, maa5 + 2 * 2048);
    conv_w<<<2048, blk, 0, stream>>>(Wv, wsKV, N8sq);
    gemm256<0><<<GB_SQ, 512, 0, stream>>>(mslot, 2048, wsKV, 2048, 2048, 8,
                                          vbuf, nullptr, 2048, nullptr, nullptr);
    // f=3 (r)
    gemm_bt<6><<<g16, blk, 0, stream>>>(t5 + 3 * 32, 160, tmw2T + 3 * 65536, 32, 2048, 32,
                                        mslot, nullptr, 2048, xa, nullptr, maa5 + 3 * 2048);
    conv_w<<<2048, blk, 0, stream>>>(Wr, wsR, N8sq);
    gemm256<0><<<GB_SQ, 512, 0, stream>>>(mslot, 2048, wsR, 2048, 2048, 8,
                                          rbuf, nullptr, 2048, nullptr, nullptr);
    // f=4 (g): mix is the LAST read of xa; then Wg scratch overlays xa.
    gemm_bt<6><<<g16, blk, 0, stream>>>(t5 + 4 * 32, 160, tmw2T + 4 * 65536, 32, 2048, 32,
                                        mslot, nullptr, 2048, xa, nullptr, maa5 + 4 * 2048);
    conv_w<<<2048, blk, 0, stream>>>(Wg, wsG, N8sq);
    gemm256<1><<<GB_SQ, 512, 0, stream>>>(mslot, 2048, wsG, 2048, 2048, 8,
                                          gbuf, nullptr, 2048, nullptr, nullptr);

    // WKV chunked scan -> y (fp32, overlays xa+mslot which are now dead)
    {
        dim3 gw(128, WKV_NC);
        wkv_pass1<<<gw, 64, 0, stream>>>(kbuf, vbuf, wpre, Sbuf, Pbuf);
        wkv_scan<<<128, 64, 0, stream>>>(Sbuf, Pbuf);
        wkv_pass2<<<gw, 64, 0, stream>>>(rbuf, kbuf, vbuf, wpre, u_in, Sbuf, ybuf);
    }
    // GroupNorm * g -> Ao (over rbuf)
    gn_kernel<<<65536, blk, 0, stream>>>(ybuf, gbuf, lnxw, lnxb, Ao);
    // x1 = x0 + Ao @ Wo^T  (bf16, over kbuf); Wo scratch over dead ybuf
    conv_w<<<2048, blk, 0, stream>>>(Wo, wsO, N8sq);
    gemm256<7><<<GB_SQ, 512, 0, stream>>>(Ao, 2048, wsO, 2048, 2048, 8,
                                          x1b, nullptr, 2048, x0b, nullptr);
    // CMix
    ln_bf16_kernel<<<8192, blk, 0, stream>>>(x1b, ln2w, ln2b, xf);
    ew_shift_one<<<65536, blk, 0, stream>>>(xf, cmk, xk2);
    conv_w<<<2048, blk, 0, stream>>>(Wfk, wsFK, N8ff);
    gemm256<2><<<GB_FK, 512, 0, stream>>>(xk2, 2048, wsFK, 2048, 2048, 28,
                                          kf, nullptr, 7168, nullptr, nullptr);
    // xr2 written over dead Wfk scratch; xf still live until here
    ew_shift_one<<<65536, blk, 0, stream>>>(xf, cmr, xr2);
    conv_w<<<2048, blk, 0, stream>>>(Wfr, wsFR, N8sq);
    gemm256<3><<<GB_SQ, 512, 0, stream>>>(xr2, 2048, wsFR, 2048, 2048, 8,
                                          sgb, nullptr, 2048, nullptr, nullptr);
    conv_w<<<2048, blk, 0, stream>>>(Wfv, wsFV, N8ff);
    gemm256<8><<<GB_SQ, 512, 0, stream>>>(kf, 7168, wsFV, 7168, 7168, 8,
                                          nullptr, (float*)d_out, 2048, x1b, sgb);
}

// Round 6
// 1885.567 us; speedup vs baseline: 3.1059x; 1.0542x over previous
//
#include <hip/hip_runtime.h>
#include <cstdint>
#include <cstddef>

#define DI __device__ __forceinline__

typedef uint16_t u16;
typedef __bf16 bf16x8 __attribute__((ext_vector_type(8)));
typedef float f32x4 __attribute__((ext_vector_type(4)));

DI float b2f(u16 u) { uint32_t x = ((uint32_t)u) << 16; float f; __builtin_memcpy(&f, &x, 4); return f; }
DI u16 f2b(float f) {
    uint32_t x; __builtin_memcpy(&x, &f, 4);
    uint32_t r = (x + 0x7FFFu + ((x >> 16) & 1u)) >> 16;
    return (u16)r;
}

// Async global->LDS, 16B per lane. LDS dest must be linear: uniform base + lane*16.
typedef const __attribute__((address_space(1))) uint32_t* gp1_t;
typedef __attribute__((address_space(3))) uint32_t* lp3_t;
DI void gld16(const void* g, void* l) {
    __builtin_amdgcn_global_load_lds((gp1_t)(uintptr_t)g, (lp3_t)l, 16, 0, 0);
}

#define BARRIER()  asm volatile("s_barrier" ::: "memory")
#define VMCNT4()   asm volatile("s_waitcnt vmcnt(4)" ::: "memory")
#define VMCNT2()   asm volatile("s_waitcnt vmcnt(2)" ::: "memory")
#define VMCNT0()   asm volatile("s_waitcnt vmcnt(0)" ::: "memory")

// Canary: fill d_out (f32) with 100+ws_MiB; final GEMM overwrites everything.
__global__ __launch_bounds__(256) void canary_kernel(float* __restrict__ out, float val) {
    size_t idx = (size_t)blockIdx.x * 256 + threadIdx.x;
    out[idx] = val;
}

// ---------------------------------------------------------------------------
// Weight convert f32 -> bf16 (elementwise, vectorized 8/thread, grid-stride)
// ---------------------------------------------------------------------------
__global__ __launch_bounds__(256) void conv_w(
    const float* __restrict__ in, u16* __restrict__ out, int n8)
{
    int idx = blockIdx.x * 256 + threadIdx.x;
    int stride = gridDim.x * 256;
    for (int i = idx; i < n8; i += stride) {
        const float4* p = (const float4*)(in + (size_t)i * 8);
        float4 a = p[0], b = p[1];
        uint32_t w0 = (uint32_t)f2b(a.x) | ((uint32_t)f2b(a.y) << 16);
        uint32_t w1 = (uint32_t)f2b(a.z) | ((uint32_t)f2b(a.w) << 16);
        uint32_t w2 = (uint32_t)f2b(b.x) | ((uint32_t)f2b(b.y) << 16);
        uint32_t w3 = (uint32_t)f2b(b.z) | ((uint32_t)f2b(b.w) << 16);
        *(uint4*)(out + (size_t)i * 8) = make_uint4(w0, w1, w2, w3);
    }
}

// ---------------------------------------------------------------------------
// Small-weight transpose + f32->bf16 convert
// ---------------------------------------------------------------------------
__global__ __launch_bounds__(256) void transpose_weights(
    const float* __restrict__ tmw1, const float* __restrict__ tdw1,
    const float* __restrict__ tdw2, const float* __restrict__ tmw2,
    u16* __restrict__ tmw1T, u16* __restrict__ tdw1T,
    u16* __restrict__ tdw2T, u16* __restrict__ tmw2T)
{
    int idx = blockIdx.x * 256 + threadIdx.x;
    if (idx < 327680) { int r = idx / 160, c = idx % 160; tmw1T[c * 2048 + r] = f2b(tmw1[idx]); return; }
    idx -= 327680;
    if (idx < 131072) { int r = idx / 64, c = idx % 64; tdw1T[c * 2048 + r] = f2b(tdw1[idx]); return; }
    idx -= 131072;
    if (idx < 131072) { int e = idx / 2048, c = idx % 2048; tdw2T[c * 64 + e] = f2b(tdw2[idx]); return; }
    idx -= 131072;
    { int f = idx / 65536; int rem = idx % 65536; int e = rem / 2048, c = rem % 2048;
      tmw2T[f * 65536 + c * 32 + e] = f2b(tmw2[idx]); }
}

DI float block_sum(float v, float* sm) {
    #pragma unroll
    for (int off = 32; off; off >>= 1) v += __shfl_xor(v, off, 64);
    __syncthreads();
    if ((threadIdx.x & 63) == 0) sm[threadIdx.x >> 6] = v;
    __syncthreads();
    float r = sm[0] + sm[1] + sm[2] + sm[3];
    __syncthreads();
    return r;
}

// LN0 then LN1 fused: x_in(f32) -> x0b (bf16 residual), xa (bf16)
__global__ __launch_bounds__(256) void ln01_kernel(
    const float* __restrict__ xin,
    const float* __restrict__ w0, const float* __restrict__ b0,
    const float* __restrict__ w1, const float* __restrict__ b1,
    u16* __restrict__ x0b, u16* __restrict__ xa)
{
    __shared__ float sm[4];
    int row = blockIdx.x;
    int tid = threadIdx.x;
    const float* xr = xin + (size_t)row * 2048;
    float v[8];
    float s = 0.f;
    #pragma unroll
    for (int i = 0; i < 8; i++) { v[i] = xr[tid + i * 256]; s += v[i]; }
    s = block_sum(s, sm);
    float mean = s * (1.f / 2048.f);
    float q = 0.f;
    #pragma unroll
    for (int i = 0; i < 8; i++) { float d = v[i] - mean; q += d * d; }
    q = block_sum(q, sm);
    float rstd = rsqrtf(q * (1.f / 2048.f) + 1e-5f);
    float t[8];
    float s2 = 0.f;
    #pragma unroll
    for (int i = 0; i < 8; i++) {
        int c = tid + i * 256;
        t[i] = (v[i] - mean) * rstd * w0[c] + b0[c];
        x0b[(size_t)row * 2048 + c] = f2b(t[i]);
        s2 += t[i];
    }
    s2 = block_sum(s2, sm);
    float mean2 = s2 * (1.f / 2048.f);
    float q2 = 0.f;
    #pragma unroll
    for (int i = 0; i < 8; i++) { float d = t[i] - mean2; q2 += d * d; }
    q2 = block_sum(q2, sm);
    float rstd2 = rsqrtf(q2 * (1.f / 2048.f) + 1e-5f);
    #pragma unroll
    for (int i = 0; i < 8; i++) {
        int c = tid + i * 256;
        xa[(size_t)row * 2048 + c] = f2b((t[i] - mean2) * rstd2 * w1[c] + b1[c]);
    }
}

// LN over bf16 input, f32 weights -> bf16 out (LN2)
__global__ __launch_bounds__(256) void ln_bf16_kernel(
    const u16* __restrict__ xin,
    const float* __restrict__ w, const float* __restrict__ b,
    u16* __restrict__ xout)
{
    __shared__ float sm[4];
    int row = blockIdx.x;
    int tid = threadIdx.x;
    const u16* xr = xin + (size_t)row * 2048;
    float v[8];
    float s = 0.f;
    #pragma unroll
    for (int i = 0; i < 8; i++) { v[i] = b2f(xr[tid + i * 256]); s += v[i]; }
    s = block_sum(s, sm);
    float mean = s * (1.f / 2048.f);
    float q = 0.f;
    #pragma unroll
    for (int i = 0; i < 8; i++) { float d = v[i] - mean; q += d * d; }
    q = block_sum(q, sm);
    float rstd = rsqrtf(q * (1.f / 2048.f) + 1e-5f);
    #pragma unroll
    for (int i = 0; i < 8; i++) {
        int c = tid + i * 256;
        xout[(size_t)row * 2048 + c] = f2b((v[i] - mean) * rstd * w[c] + b[c]);
    }
}

// xxx = xa + (shift(xa)-xa)*maa_x
__global__ __launch_bounds__(256) void ew_xxx(
    const u16* __restrict__ xa, const float* __restrict__ maax, u16* __restrict__ xxx)
{
    size_t idx = (size_t)blockIdx.x * 256 + threadIdx.x;
    int c = (int)(idx & 2047);
    int row = (int)(idx >> 11);
    float cur = b2f(xa[idx]);
    float prev = (row & 2047) ? b2f(xa[idx - 2048]) : 0.f;
    xxx[idx] = f2b(cur + (prev - cur) * maax[c]);
}

// single-output token-shift mix (CMix): out = xf + (shift(xf)-xf)*coef
__global__ __launch_bounds__(256) void ew_shift_one(
    const u16* __restrict__ xf, const float* __restrict__ coef, u16* __restrict__ out)
{
    size_t idx = (size_t)blockIdx.x * 256 + threadIdx.x;
    int c = (int)(idx & 2047);
    int row = (int)(idx >> 11);
    float cur = b2f(xf[idx]);
    float prev = (row & 2047) ? b2f(xf[idx - 2048]) : 0.f;
    out[idx] = f2b(cur + (prev - cur) * coef[c]);
}

// GroupNorm(64 per head) * lnx + bias, then * g  -> Ao (bf16)
__global__ __launch_bounds__(256) void gn_kernel(
    const float* __restrict__ y, const u16* __restrict__ g,
    const float* __restrict__ lw, const float* __restrict__ lb,
    u16* __restrict__ Ao)
{
    int grp = blockIdx.x * 4 + (threadIdx.x >> 6);
    int m = threadIdx.x & 63;
    int h = grp & 31;
    size_t idx = (size_t)grp * 64 + m;
    float v = y[idx];
    float s = v;
    #pragma unroll
    for (int off = 32; off; off >>= 1) s += __shfl_xor(s, off, 64);
    float mean = s * (1.f / 64.f);
    float d = v - mean;
    float q = d * d;
    #pragma unroll
    for (int off = 32; off; off >>= 1) q += __shfl_xor(q, off, 64);
    float rstd = rsqrtf(q * (1.f / 64.f) + 6.4e-4f);   // eps = 1e-5 * 8^2
    float yn = d * rstd * lw[h * 64 + m] + lb[h * 64 + m];
    Ao[idx] = f2b(yn * b2f(g[idx]));
}

// ---------------------------------------------------------------------------
// WKV6 chunked scan (pass1 / scan / pass2). Sbuf = d_out, Pbuf over dead t5.
// ---------------------------------------------------------------------------
#define WKV_L  64
#define WKV_NC 32

__global__ __launch_bounds__(64) void wkv_pass1(
    const u16* __restrict__ kb, const u16* __restrict__ vb,
    const u16* __restrict__ wb,
    float* __restrict__ Sbuf, float* __restrict__ Pbuf)
{
    int bh = blockIdx.x;           // 0..127
    int c  = blockIdx.y;           // 0..WKV_NC-1
    int b = bh >> 5, h = bh & 31;
    int m = threadIdx.x;
    __shared__ __align__(16) float ks[64];
    __shared__ __align__(16) float ws[64];
    float S[64];
    #pragma unroll
    for (int n = 0; n < 64; n++) S[n] = 0.f;
    float P = 1.f;
    size_t base = ((size_t)b * 2048 + (size_t)(c * WKV_L)) * 2048 + (size_t)h * 64 + m;
    float kc = b2f(kb[base]), vc = b2f(vb[base]);
    float wc = __expf(-__expf(b2f(wb[base])));
    for (int t = 0; t < WKV_L; t++) {
        float kn = 0.f, vn = 0.f; u16 wn = 0;
        if (t < WKV_L - 1) {
            size_t ni = base + (size_t)(t + 1) * 2048;
            kn = b2f(kb[ni]); vn = b2f(vb[ni]); wn = wb[ni];
        }
        ks[m] = kc; ws[m] = wc;
        __syncthreads();
        #pragma unroll
        for (int g4 = 0; g4 < 16; g4++) {
            float4 k4 = *(const float4*)&ks[g4 * 4];
            float4 w4 = *(const float4*)&ws[g4 * 4];
            S[g4 * 4 + 0] = S[g4 * 4 + 0] * w4.x + k4.x * vc;
            S[g4 * 4 + 1] = S[g4 * 4 + 1] * w4.y + k4.y * vc;
            S[g4 * 4 + 2] = S[g4 * 4 + 2] * w4.z + k4.z * vc;
            S[g4 * 4 + 3] = S[g4 * 4 + 3] * w4.w + k4.w * vc;
        }
        P *= wc;
        __syncthreads();
        kc = kn; vc = vn; wc = __expf(-__expf(b2f(wn)));
    }
    size_t so = (size_t)(c * 128 + bh) * 4096 + m;
    #pragma unroll
    for (int n = 0; n < 64; n++) Sbuf[so + (size_t)n * 64] = S[n];
    Pbuf[(size_t)(c * 128 + bh) * 64 + m] = P;
}

__global__ __launch_bounds__(64) void wkv_scan(
    float* __restrict__ Sbuf, const float* __restrict__ Pbuf)
{
    int bh = blockIdx.x;
    int m = threadIdx.x;
    __shared__ float ps[64];
    float S[64];
    #pragma unroll
    for (int n = 0; n < 64; n++) S[n] = 0.f;
    for (int c = 0; c < WKV_NC; c++) {
        ps[m] = Pbuf[(size_t)(c * 128 + bh) * 64 + m];
        __syncthreads();
        size_t so = (size_t)(c * 128 + bh) * 4096 + m;
        #pragma unroll
        for (int n = 0; n < 64; n++) {
            float Mv = Sbuf[so + (size_t)n * 64];
            Sbuf[so + (size_t)n * 64] = S[n];
            S[n] = S[n] * ps[n] + Mv;
        }
        __syncthreads();
    }
}

__global__ __launch_bounds__(64) void wkv_pass2(
    const u16* __restrict__ rb, const u16* __restrict__ kb,
    const u16* __restrict__ vb, const u16* __restrict__ wb,
    const float* __restrict__ ub, const float* __restrict__ Sbuf,
    float* __restrict__ yb)
{
    int bh = blockIdx.x;
    int c  = blockIdx.y;
    int b = bh >> 5, h = bh & 31;
    int m = threadIdx.x;
    __shared__ __align__(16) float rs[64];
    __shared__ __align__(16) float ks[64];
    __shared__ __align__(16) float ws[64];
    float u_m = ub[h * 64 + m];
    float S[64];
    size_t so = (size_t)(c * 128 + bh) * 4096 + m;
    #pragma unroll
    for (int n = 0; n < 64; n++) S[n] = Sbuf[so + (size_t)n * 64];
    size_t base = ((size_t)b * 2048 + (size_t)(c * WKV_L)) * 2048 + (size_t)h * 64 + m;
    float rc = b2f(rb[base]), kc = b2f(kb[base]), vc = b2f(vb[base]);
    float wc = __expf(-__expf(b2f(wb[base])));
    for (int t = 0; t < WKV_L; t++) {
        float rn = 0.f, kn = 0.f, vn = 0.f; u16 wn = 0;
        if (t < WKV_L - 1) {
            size_t ni = base + (size_t)(t + 1) * 2048;
            rn = b2f(rb[ni]); kn = b2f(kb[ni]); vn = b2f(vb[ni]); wn = wb[ni];
        }
        rs[m] = rc; ks[m] = kc; ws[m] = wc;
        __syncthreads();
        float p = rc * u_m * kc;
        #pragma unroll
        for (int off = 32; off; off >>= 1) p += __shfl_xor(p, off, 64);
        float y = p * vc;
        #pragma unroll
        for (int g4 = 0; g4 < 16; g4++) {
            float4 r4 = *(const float4*)&rs[g4 * 4];
            float4 k4 = *(const float4*)&ks[g4 * 4];
            float4 w4 = *(const float4*)&ws[g4 * 4];
            y += r4.x * S[g4 * 4 + 0] + r4.y * S[g4 * 4 + 1]
               + r4.z * S[g4 * 4 + 2] + r4.w * S[g4 * 4 + 3];
            S[g4 * 4 + 0] = S[g4 * 4 + 0] * w4.x + k4.x * vc;
            S[g4 * 4 + 1] = S[g4 * 4 + 1] * w4.y + k4.y * vc;
            S[g4 * 4 + 2] = S[g4 * 4 + 2] * w4.z + k4.z * vc;
            S[g4 * 4 + 3] = S[g4 * 4 + 3] * w4.w + k4.w * vc;
        }
        yb[base + (size_t)t * 2048] = y;
        __syncthreads();
        rc = rn; kc = kn; vc = vn; wc = __expf(-__expf(b2f(wn)));
    }
}

// ---------------------------------------------------------------------------
// 256x256 4-phase-per-tile GEMM with operand-register reuse:
// phase order (0,0)->(0,1)->(1,1)->(1,0). A0 read once (ph0, kept ph1);
// B1 once (ph1, kept ph2); A1 once (ph2, kept ph3); B0 once (ph0, kept in
// second reg set b0_, reused ph3). 24KB ds_read/wave/tile (was 48KB).
// Stage order tile t+1: A0@ph0, B0@ph1, B1@ph2, A1@ph3; counted vmcnt
// (in 2-load units): ph0 vmcnt(4) retires B1(t); ph1 vmcnt(4) retires A1(t);
// ph3 vmcnt(4) retires A0,B0(t+1). Tail: vmcnt(2)/vmcnt(0).
// XOR-swizzled LDS (slot ^= row&7) via pre-swizzled global source (rule 21).
// Requires M%256==0, N%256==0, K%64==0 (>=128), grid%8==0 (T1 swizzle).
// ---------------------------------------------------------------------------
template<int QM>
DI void loadA(bf16x8 (&a_)[4][2], const u16* Ab, int abase) {
    #pragma unroll
    for (int i = 0; i < 4; ++i) {
        int o = abase + QM * 16384 + i * 2048;
        a_[i][0] = *(const bf16x8*)((const char*)Ab + o);
        a_[i][1] = *(const bf16x8*)((const char*)Ab + (o ^ 64));
    }
}
template<int QN>
DI void loadB(bf16x8 (&b_)[2][2], const u16* Bb, int bbase) {
    #pragma unroll
    for (int j = 0; j < 2; ++j) {
        int o = bbase + QN * 16384 + j * 2048;
        b_[j][0] = *(const bf16x8*)((const char*)Bb + o);
        b_[j][1] = *(const bf16x8*)((const char*)Bb + (o ^ 64));
    }
}
DI void mfq2(f32x4 (&accp)[4][2], const bf16x8 (&a_)[4][2], const bf16x8 (&b_)[2][2]) {
    #pragma unroll
    for (int i = 0; i < 4; ++i)
        #pragma unroll
        for (int j = 0; j < 2; ++j) {
            accp[i][j] = __builtin_amdgcn_mfma_f32_16x16x32_bf16(
                a_[i][0], b_[j][0], accp[i][j], 0, 0, 0);
            accp[i][j] = __builtin_amdgcn_mfma_f32_16x16x32_bf16(
                a_[i][1], b_[j][1], accp[i][j], 0, 0, 0);
        }
}

// MODE: 0 plain, 1 silu, 2 relu^2, 3 sigmoid, 7 residual-add bf16,
//       8 final f32: aux0 + aux1*acc
template<int MODE>
__global__ __launch_bounds__(512, 2)
void gemm256(const u16* __restrict__ A, int lda,
             const u16* __restrict__ B, int ldb,
             int K, int nxb,
             u16* __restrict__ Cb, float* __restrict__ Cf, int ldc,
             const u16* __restrict__ auxb0, const u16* __restrict__ auxb1)
{
    __shared__ __align__(16) u16 Al[2][16384];
    __shared__ __align__(16) u16 Bl[2][16384];

    // T1: bijective XCD swizzle (gridDim.x % 8 == 0 at all call sites)
    int nwg = gridDim.x;
    int cpx = nwg >> 3;
    int sw = (blockIdx.x & 7) * cpx + (blockIdx.x >> 3);
    int mb = sw / nxb, nb = sw - mb * nxb;
    int m0 = mb * 256, n0 = nb * 256;

    int tid = threadIdx.x;
    int lane = tid & 63;
    int wid = tid >> 6;
    int vm = wid >> 2, vn = wid & 3;
    int l15 = lane & 15, q = lane >> 4;

    // staging: slot s covers 16B; row = s>>3, global k-chunk pre-swizzled
    int s0 = tid, s1 = tid + 512;
    int r0 = s0 >> 3, r1 = s1 >> 3;
    int k0e = (((s0 & 7) ^ (r0 & 7)) << 3);
    int k1e = (((s1 & 7) ^ (r1 & 7)) << 3);
    const u16* gA00 = A + (size_t)(m0 +       r0) * lda + k0e;
    const u16* gA01 = A + (size_t)(m0 +       r1) * lda + k1e;
    const u16* gA10 = A + (size_t)(m0 + 128 + r0) * lda + k0e;
    const u16* gA11 = A + (size_t)(m0 + 128 + r1) * lda + k1e;
    const u16* gB00 = B + (size_t)(n0 +       r0) * ldb + k0e;
    const u16* gB01 = B + (size_t)(n0 +       r1) * ldb + k1e;
    const u16* gB10 = B + (size_t)(n0 + 128 + r0) * ldb + k0e;
    const u16* gB11 = B + (size_t)(n0 + 128 + r1) * ldb + k1e;
    int d00 = s0 * 8, d01 = s1 * 8;           // u16 index, half0 (rows 0-127)
    int d10 = 8192 + s0 * 8, d11 = 8192 + s1 * 8;   // half1 (rows 128-255)

    // ds_read byte offsets (swizzled): row stride 128B, slot = chunk ^ (row&7)
    int swz0 = q ^ (l15 & 7);
    int abase = (vm * 64 + l15) * 128 + swz0 * 16;
    int bbase = (vn * 32 + l15) * 128 + swz0 * 16;

    f32x4 acc[4][4][2];
    #pragma unroll
    for (int p = 0; p < 4; ++p)
        #pragma unroll
        for (int i = 0; i < 4; ++i)
            #pragma unroll
            for (int j = 0; j < 2; ++j) acc[p][i][j] = (f32x4){0.f, 0.f, 0.f, 0.f};

    int nt = K >> 6;

    // prologue: stage tile 0 in order A0, B0, B1, A1
    gld16(gA00, &Al[0][d00]); gld16(gA01, &Al[0][d01]);
    gld16(gB00, &Bl[0][d00]); gld16(gB01, &Bl[0][d01]);
    gld16(gB10, &Bl[0][d10]); gld16(gB11, &Bl[0][d11]);
    gld16(gA10, &Al[0][d10]); gld16(gA11, &Al[0][d11]);
    VMCNT4();      // A0,B0 landed
    BARRIER();

    for (int t = 0; t < nt; ++t) {
        const u16* Ab = &Al[t & 1][0];
        const u16* Bb = &Bl[t & 1][0];
        int stb = (t & 1) ^ 1;
        bool st = (t + 1 < nt);
        size_t ko = (size_t)(t + 1) * 64;
        bf16x8 a_[4][2], b0_[2][2], b1_[2][2];

        // ph0: quadrant (0,0) [reads A0,B0]; stage A0(t+1)
        loadA<0>(a_, Ab, abase);
        loadB<0>(b0_, Bb, bbase);
        if (st) { gld16(gA00 + ko, &Al[stb][d00]); gld16(gA01 + ko, &Al[stb][d01]); VMCNT4(); }
        else    { VMCNT2(); }
        BARRIER();                      // B1(t) now visible to all
        __builtin_amdgcn_s_setprio(1);
        mfq2(acc[0], a_, b0_);
        __builtin_amdgcn_s_setprio(0);

        // ph1: quadrant (0,1) [keeps A0, reads B1]; stage B0(t+1)
        loadB<1>(b1_, Bb, bbase);
        if (st) { gld16(gB00 + ko, &Bl[stb][d00]); gld16(gB01 + ko, &Bl[stb][d01]); VMCNT4(); }
        else    { VMCNT0(); }
        BARRIER();                      // A1(t) now visible
        __builtin_amdgcn_s_setprio(1);
        mfq2(acc[1], a_, b1_);
        __builtin_amdgcn_s_setprio(0);

        // ph2: quadrant (1,1) [reads A1, keeps B1]; stage B1(t+1)
        loadA<1>(a_, Ab, abase);
        if (st) { gld16(gB10 + ko, &Bl[stb][d10]); gld16(gB11 + ko, &Bl[stb][d11]); }
        BARRIER();
        __builtin_amdgcn_s_setprio(1);
        mfq2(acc[2], a_, b1_);
        __builtin_amdgcn_s_setprio(0);

        // ph3: quadrant (1,0) [keeps A1, reuses B0 from regs]; stage A1(t+1)
        if (st) { gld16(gA10 + ko, &Al[stb][d10]); gld16(gA11 + ko, &Al[stb][d11]); VMCNT4(); }
        BARRIER();                      // A0,B0(t+1) now visible
        __builtin_amdgcn_s_setprio(1);
        mfq2(acc[3], a_, b0_);
        __builtin_amdgcn_s_setprio(0);
    }

    // epilogue: acc[p] -> quadrant (qm,qn) per phase order (0,0),(0,1),(1,1),(1,0)
    const int qmA[4] = {0, 0, 1, 1};
    const int qnA[4] = {0, 1, 1, 0};
    #pragma unroll
    for (int p = 0; p < 4; ++p) {
        int qm = qmA[p], qn = qnA[p];
        #pragma unroll
        for (int mi = 0; mi < 4; ++mi) {
            #pragma unroll
            for (int nj = 0; nj < 2; ++nj) {
                int col = n0 + qn * 128 + vn * 32 + nj * 16 + l15;
                int rowb = m0 + qm * 128 + vm * 64 + mi * 16 + q * 4;
                #pragma unroll
                for (int r = 0; r < 4; ++r) {
                    int row = rowb + r;
                    float v = acc[p][mi][nj][r];
                    size_t o = (size_t)row * ldc + col;
                    if (MODE == 0) {
                        Cb[o] = f2b(v);
                    } else if (MODE == 1) {
                        float sg = 1.f / (1.f + __expf(-v)); Cb[o] = f2b(v * sg);
                    } else if (MODE == 2) {
                        float tq = v > 0.f ? v : 0.f; Cb[o] = f2b(tq * tq);
                    } else if (MODE == 3) {
                        Cb[o] = f2b(1.f / (1.f + __expf(-v)));
                    } else if (MODE == 7) {
                        Cb[o] = f2b(b2f(auxb0[o]) + v);
                    } else if (MODE == 8) {
                        Cf[o] = b2f(auxb0[o]) + b2f(auxb1[o]) * v;
                    }
                }
            }
        }
    }
}

// ---------------------------------------------------------------------------
// Legacy 128x128 GEMM for small/odd shapes (N=160/64, K=32/64, token-shift mix)
// MODE: 4 tanh, 5 f32bias+acc->bf16, 6 token-shift mix
// ---------------------------------------------------------------------------
template<int MODE>
__global__ __launch_bounds__(256)
void gemm_bt(const u16* __restrict__ A, int lda,
             const u16* __restrict__ B, int ldb,
             int N, int K,
             u16* __restrict__ Cb, float* __restrict__ Cf, int ldc,
             const u16* __restrict__ auxb0,
             const u16* __restrict__ auxb1,
             const float* __restrict__ auxf0)
{
    __shared__ __align__(16) u16 At[128 * 32];
    __shared__ __align__(16) u16 Bt[128 * 32];
    const int tid = threadIdx.x;
    const int lane = tid & 63;
    const int wv = tid >> 6;
    const int wr = wv >> 1, wc = wv & 1;
    const int m0 = blockIdx.y * 128;
    const int n0 = blockIdx.x * 128;
    const int l15 = lane & 15;
    const int lq = lane >> 4;
    f32x4 acc[4][4];
    #pragma unroll
    for (int i = 0; i < 4; i++)
        #pragma unroll
        for (int j = 0; j < 4; j++) acc[i][j] = (f32x4){0.f, 0.f, 0.f, 0.f};

    const int s0 = tid, s1 = tid + 256;
    const int rA0 = s0 >> 2, kc0 = (s0 & 3) * 8;
    const int rA1 = s1 >> 2, kc1 = (s1 & 3) * 8;
    const u16* ga0 = A + (size_t)(m0 + rA0) * lda + kc0;
    const u16* ga1 = A + (size_t)(m0 + rA1) * lda + kc1;
    int br0 = n0 + rA0; br0 = br0 < N ? br0 : N - 1;
    int br1 = n0 + rA1; br1 = br1 < N ? br1 : N - 1;
    const u16* gb0 = B + (size_t)br0 * ldb + kc0;
    const u16* gb1 = B + (size_t)br1 * ldb + kc1;
    u16* la0 = &At[(size_t)s0 * 8];
    u16* la1 = &At[(size_t)s1 * 8];
    u16* lb0 = &Bt[(size_t)s0 * 8];
    u16* lb1 = &Bt[(size_t)s1 * 8];

    for (int k0 = 0; k0 < K; k0 += 32) {
        gld16(ga0 + k0, la0);
        gld16(ga1 + k0, la1);
        gld16(gb0 + k0, lb0);
        gld16(gb1 + k0, lb1);
        __syncthreads();
        bf16x8 af[4], bfr[4];
        #pragma unroll
        for (int mi = 0; mi < 4; mi++)
            af[mi] = *(const bf16x8*)(&At[(wr * 64 + mi * 16 + l15) * 32 + lq * 8]);
        #pragma unroll
        for (int ni = 0; ni < 4; ni++)
            bfr[ni] = *(const bf16x8*)(&Bt[(wc * 64 + ni * 16 + l15) * 32 + lq * 8]);
        #pragma unroll
        for (int mi = 0; mi < 4; mi++)
            #pragma unroll
            for (int ni = 0; ni < 4; ni++)
                acc[mi][ni] = __builtin_amdgcn_mfma_f32_16x16x32_bf16(af[mi], bfr[ni], acc[mi][ni], 0, 0, 0);
        __syncthreads();
    }

    #pragma unroll
    for (int ni = 0; ni < 4; ni++) {
        int col = n0 + wc * 64 + ni * 16 + l15;
        if (col >= N) continue;
        #pragma unroll
        for (int mi = 0; mi < 4; mi++) {
            int rowb = m0 + wr * 64 + mi * 16 + lq * 4;
            #pragma unroll
            for (int r = 0; r < 4; r++) {
                int row = rowb + r;
                float v = acc[mi][ni][r];
                size_t o = (size_t)row * ldc + col;
                if (MODE == 0) {
                    Cb[o] = f2b(v);
                } else if (MODE == 4) {
                    Cb[o] = f2b(tanhf(v));
                } else if (MODE == 5) {
                    Cb[o] = f2b(auxf0[col] + v);
                } else if (MODE == 6) {
                    float cur = b2f(auxb0[(size_t)row * 2048 + col]);
                    float prev = (row & 2047) ? b2f(auxb0[(size_t)(row - 1) * 2048 + col]) : 0.f;
                    Cb[o] = f2b(cur + (prev - cur) * (auxf0[col] + v));
                }
            }
        }
    }
}

// ---------------------------------------------------------------------------
extern "C" void kernel_launch(void* const* d_in, const int* in_sizes, int n_in,
                              void* d_out, int out_size, void* d_ws, size_t ws_size,
                              hipStream_t stream)
{
    const float* x_in  = (const float*)d_in[0];
    const float* ln0w  = (const float*)d_in[1];
    const float* ln0b  = (const float*)d_in[2];
    const float* ln1w  = (const float*)d_in[3];
    const float* ln1b  = (const float*)d_in[4];
    const float* ln2w  = (const float*)d_in[5];
    const float* ln2b  = (const float*)d_in[6];
    const float* maax  = (const float*)d_in[7];
    const float* maa5  = (const float*)d_in[8];
    const float* tmw1  = (const float*)d_in[9];
    const float* tmw2  = (const float*)d_in[10];
    const float* td    = (const float*)d_in[11];
    const float* tdw1  = (const float*)d_in[12];
    const float* tdw2  = (const float*)d_in[13];
    const float* u_in  = (const float*)d_in[14];
    const float* Wr    = (const float*)d_in[15];
    const float* Wk    = (const float*)d_in[16];
    const float* Wv    = (const float*)d_in[17];
    const float* Wg    = (const float*)d_in[18];
    const float* Wo    = (const float*)d_in[19];
    const float* lnxw  = (const float*)d_in[20];
    const float* lnxb  = (const float*)d_in[21];
    const float* cmk   = (const float*)d_in[22];
    const float* cmr   = (const float*)d_in[23];
    const float* Wfk   = (const float*)d_in[24];
    const float* Wfr   = (const float*)d_in[25];
    const float* Wfv   = (const float*)d_in[26];

    const size_t MB = 1048576ULL;
    char* W = (char*)d_ws;
    u16*   xa    = (u16*)(W + 0 * MB);      // LN1 out; dead after last mix
    u16*   mslot = (u16*)(W + 32 * MB);     // xxx, then per-f mix output
    u16*   x0b   = (u16*)(W + 64 * MB);     // LN0 out (residual)
    u16*   rbuf  = (u16*)(W + 96 * MB);
    u16*   kbuf  = (u16*)(W + 128 * MB);
    u16*   vbuf  = (u16*)(W + 160 * MB);
    u16*   gbuf  = (u16*)(W + 192 * MB);
    u16*   wpre  = (u16*)(W + 224 * MB);    // bf16 pre-activation decay
    u16*   t5    = (u16*)(W + 256 * MB);    // [8192,160]
    u16*   tmw1T = (u16*)(W + 259 * MB);
    u16*   tdw1T = (u16*)(W + 260 * MB);
    u16*   tdw2T = (u16*)(W + 261 * MB);
    u16*   tmw2T = (u16*)(W + 262 * MB);
    u16*   hwb   = (u16*)(W + 263 * MB);    // [8192,64]
    // aliases (dead-range reuse):
    float* ybuf = (float*)(W + 0 * MB);     // 64MB over xa+mslot (dead post-mix)
    u16*   Ao   = rbuf;                     // post-wkv
    u16*   x1b  = kbuf;                     // post-wkv residual
    u16*   xf   = vbuf;                     // LN2 out
    u16*   xk2  = gbuf;
    u16*   xr2  = wpre;                     // written AFTER Wfk gemm (scratch dies)
    u16*   kf   = (u16*)(W + 0 * MB);       // [8192,7168] = 112MB over dead head
    u16*   sgb  = vbuf;                     // sigmoid out (xf dead)
    // WKV chunked-scan scratch: 64MB in d_out (dead until final GEMM); 1MB Pbuf.
    float* Sbuf = (float*)d_out;
    float* Pbuf = (float*)(W + 256 * MB);   // over t5 (dead after mixes)
    // JIT bf16 weight scratch (lifetime-audited dead ranges):
    u16* wsKV = rbuf;                       // Wk, then Wv (rbuf free until f=3)
    u16* wsR  = gbuf;                       // Wr (gbuf free until f=4)
    u16* wsG  = xa;                         // Wg (xa dead after last mix)
    u16* wsO  = (u16*)(W + 0 * MB);         // Wo (ybuf dead after gn)
    u16* wsFK = wpre;                       // Wfk (wpre dead after wkv; 28MB<32MB)
    u16* wsFR = (u16*)(W + 112 * MB);       // Wfr (Ao tail dead; 8MB<16MB)
    u16* wsFV = gbuf;                       // Wfv (xk2 dead after Wfk gemm; 28MB)

    dim3 blk(256);
    dim3 g1(1, 64), g2(2, 64), g16(16, 64);
    const int N8sq = 2048 * 2048 / 8;
    const int N8ff = 7168 * 2048 / 8;
    // 256-tile grid sizes: (M/256)*(N/256); nxb = N/256
    const int GB_SQ = 32 * 8;    // 256 blocks, nxb=8
    const int GB_FK = 32 * 28;   // 896 blocks, nxb=28

    float canary = 100.0f + (float)(ws_size >> 20);
    canary_kernel<<<65536, blk, 0, stream>>>((float*)d_out, canary);

    transpose_weights<<<3584, blk, 0, stream>>>(tmw1, tdw1, tdw2, tmw2, tmw1T, tdw1T, tdw2T, tmw2T);
    ln01_kernel<<<8192, blk, 0, stream>>>(x_in, ln0w, ln0b, ln1w, ln1b, x0b, xa);
    ew_xxx<<<65536, blk, 0, stream>>>(xa, maax, mslot);

    // t5 = tanh(xxx @ tm_w1)   [8192,160]
    gemm_bt<4><<<g2, blk, 0, stream>>>(mslot, 2048, tmw1T, 2048, 160, 2048,
                                       t5, nullptr, 160, nullptr, nullptr, nullptr);
    // f=0 (w): mix -> mslot; hw = tanh(xw @ td_w1); wpre = td + hw @ td_w2
    gemm_bt<6><<<g16, blk, 0, stream>>>(t5 + 0 * 32, 160, tmw2T + 0 * 65536, 32, 2048, 32,
                                        mslot, nullptr, 2048, xa, nullptr, maa5 + 0 * 2048);
    gemm_bt<4><<<g1, blk, 0, stream>>>(mslot, 2048, tdw1T, 2048, 64, 2048,
                                       hwb, nullptr, 64, nullptr, nullptr, nullptr);
    gemm_bt<5><<<g16, blk, 0, stream>>>(hwb, 64, tdw2T, 64, 2048, 64,
                                        wpre, nullptr, 2048, nullptr, nullptr, td);
    // f=1 (k)
    gemm_bt<6><<<g16, blk, 0, stream>>>(t5 + 1 * 32, 160, tmw2T + 1 * 65536, 32, 2048, 32,
                                        mslot, nullptr, 2048, xa, nullptr, maa5 + 1 * 2048);
    conv_w<<<2048, blk, 0, stream>>>(Wk, wsKV, N8sq);
    gemm256<0><<<GB_SQ, 512, 0, stream>>>(mslot, 2048, wsKV, 2048, 2048, 8,
                                          kbuf, nullptr, 2048, nullptr, nullptr);
    // f=2 (v)
    gemm_bt<6><<<g16, blk, 0, stream>>>(t5 + 2 * 32, 160, tmw2T + 2 * 65536, 32, 2048, 32,
                                        mslot, nullptr, 2048, xa, nullptr, maa5 + 2 * 2048);
    conv_w<<<2048, blk, 0, stream>>>(Wv, wsKV, N8sq);
    gemm256<0><<<GB_SQ, 512, 0, stream>>>(mslot, 2048, wsKV, 2048, 2048, 8,
                                          vbuf, nullptr, 2048, nullptr, nullptr);
    // f=3 (r)
    gemm_bt<6><<<g16, blk, 0, stream>>>(t5 + 3 * 32, 160, tmw2T + 3 * 65536, 32, 2048, 32,
                                        mslot, nullptr, 2048, xa, nullptr, maa5 + 3 * 2048);
    conv_w<<<2048, blk, 0, stream>>>(Wr, wsR, N8sq);
    gemm256<0><<<GB_SQ, 512, 0, stream>>>(mslot, 2048, wsR, 2048, 2048, 8,
                                          rbuf, nullptr, 2048, nullptr, nullptr);
    // f=4 (g): mix is the LAST read of xa; then Wg scratch overlays xa.
    gemm_bt<6><<<g16, blk, 0, stream>>>(t5 + 4 * 32, 160, tmw2T + 4 * 65536, 32, 2048, 32,
                                        mslot, nullptr, 2048, xa, nullptr, maa5 + 4 * 2048);
    conv_w<<<2048, blk, 0, stream>>>(Wg, wsG, N8sq);
    gemm256<1><<<GB_SQ, 512, 0, stream>>>(mslot, 2048, wsG, 2048, 2048, 8,
                                          gbuf, nullptr, 2048, nullptr, nullptr);

    // WKV chunked scan -> y (fp32, overlays xa+mslot which are now dead)
    {
        dim3 gw(128, WKV_NC);
        wkv_pass1<<<gw, 64, 0, stream>>>(kbuf, vbuf, wpre, Sbuf, Pbuf);
        wkv_scan<<<128, 64, 0, stream>>>(Sbuf, Pbuf);
        wkv_pass2<<<gw, 64, 0, stream>>>(rbuf, kbuf, vbuf, wpre, u_in, Sbuf, ybuf);
    }
    // GroupNorm * g -> Ao (over rbuf)
    gn_kernel<<<65536, blk, 0, stream>>>(ybuf, gbuf, lnxw, lnxb, Ao);
    // x1 = x0 + Ao @ Wo^T  (bf16, over kbuf); Wo scratch over dead ybuf
    conv_w<<<2048, blk, 0, stream>>>(Wo, wsO, N8sq);
    gemm256<7><<<GB_SQ, 512, 0, stream>>>(Ao, 2048, wsO, 2048, 2048, 8,
                                          x1b, nullptr, 2048, x0b, nullptr);
    // CMix
    ln_bf16_kernel<<<8192, blk, 0, stream>>>(x1b, ln2w, ln2b, xf);
    ew_shift_one<<<65536, blk, 0, stream>>>(xf, cmk, xk2);
    conv_w<<<2048, blk, 0, stream>>>(Wfk, wsFK, N8ff);
    gemm256<2><<<GB_FK, 512, 0, stream>>>(xk2, 2048, wsFK, 2048, 2048, 28,
                                          kf, nullptr, 7168, nullptr, nullptr);
    // xr2 written over dead Wfk scratch; xf still live until here
    ew_shift_one<<<65536, blk, 0, stream>>>(xf, cmr, xr2);
    conv_w<<<2048, blk, 0, stream>>>(Wfr, wsFR, N8sq);
    gemm256<3><<<GB_SQ, 512, 0, stream>>>(xr2, 2048, wsFR, 2048, 2048, 8,
                                          sgb, nullptr, 2048, nullptr, nullptr);
    conv_w<<<2048, blk, 0, stream>>>(Wfv, wsFV, N8ff);
    gemm256<8><<<GB_SQ, 512, 0, stream>>>(kf, 7168, wsFV, 7168, 7168, 8,
                                          nullptr, (float*)d_out, 2048, x1b, sgb);
}